// Round 13
// baseline (6300.148 us; speedup 1.0000x reference)
//
#include <hip/hip_runtime.h>
#include <hip/hip_bf16.h>

// CharRNN: embed -> 4x (LayerNorm-LSTM over T=128) -> projection to vocab.
// Round 12: fine-grained producer-consumer sync in k_rnn. Barriers dissolve
// into the data path: gate thread polls ONLY its 4 producer col-block slots
// then loads z immediately; col-block lane polls ONLY its h-row's gate slot
// then loads h. Producers keep drain+store arrival. The pred-exchange
// __syncthreads doubles as the z-WAR guarantee (all lanes' polls cover all
// 32 gate slots). Helpers (zx for next layer) unchanged.

typedef __bf16 bf16x8 __attribute__((ext_vector_type(8)));
typedef __bf16 bf16x4 __attribute__((ext_vector_type(4)));
typedef float  f32x4  __attribute__((ext_vector_type(4)));

#define VOCAB 32000
#define BATCH 32
#define SEQ   128
#define RNN   1024
#define NLAY  4
#define GBLK  128
#define AR_STRIDE 16            // dwords between arrival slots (64 B)

__device__ __forceinline__ float sigm(float x) { return 1.f / (1.f + __expf(-x)); }

// ---- agent-scope relaxed atomics (sc1: coherence-point, bypass stale L2) ----
__device__ __forceinline__ unsigned ald(const unsigned* p) {
    return __hip_atomic_load(p, __ATOMIC_RELAXED, __HIP_MEMORY_SCOPE_AGENT);
}
__device__ __forceinline__ void ast(unsigned* p, unsigned v) {
    __hip_atomic_store(p, v, __ATOMIC_RELAXED, __HIP_MEMORY_SCOPE_AGENT);
}
__device__ __forceinline__ unsigned long long ald64(const unsigned long long* p) {
    return __hip_atomic_load(p, __ATOMIC_RELAXED, __HIP_MEMORY_SCOPE_AGENT);
}
__device__ __forceinline__ void ast64(unsigned long long* p, unsigned long long v) {
    __hip_atomic_store(p, v, __ATOMIC_RELAXED, __HIP_MEMORY_SCOPE_AGENT);
}
__device__ __forceinline__ void astf(float* p, float v) {
    __hip_atomic_store(p, v, __ATOMIC_RELAXED, __HIP_MEMORY_SCOPE_AGENT);
}
__device__ __forceinline__ void drain_vm() {
    asm volatile("s_waitcnt vmcnt(0)" ::: "memory");
}

typedef union { unsigned long long u[2]; f32x4 f; }  U128F;
typedef union { unsigned long long u; bf16x4 v; }    U64B;

// ---------------------------------------------------------------------------
// W [L][2048][4096] f32 -> Wt [L][2 planes (hi,lo)][4096][2048] bf16,
// transposed to [n][k]. k 0..1023 = x-part (Wx), k 1024..2047 = h-part (Wh).
__global__ __launch_bounds__(256) void k_cvt_w(const float* __restrict__ W,
                                               __bf16* __restrict__ Wt) {
    __shared__ float lds[64][65];
    const int tid = threadIdx.x, tx = tid & 15, ty = tid >> 4;
    const int n0 = blockIdx.x * 64, k0 = blockIdx.y * 64;
    const size_t l = blockIdx.z;
    const float* src = W + (l * 2048 + (size_t)k0) * 4096 + n0;
#pragma unroll
    for (int rr = 0; rr < 4; ++rr) {
        int kr = rr * 16 + ty;
        f32x4 v = *(const f32x4*)(src + (size_t)kr * 4096 + tx * 4);
        lds[kr][tx*4+0] = v[0]; lds[kr][tx*4+1] = v[1];
        lds[kr][tx*4+2] = v[2]; lds[kr][tx*4+3] = v[3];
    }
    __syncthreads();
    __bf16* dhi = Wt + ((l * 2 + 0) * 4096 + (size_t)n0) * 2048 + k0;
    __bf16* dlo = Wt + ((l * 2 + 1) * 4096 + (size_t)n0) * 2048 + k0;
#pragma unroll
    for (int rr = 0; rr < 4; ++rr) {
        int nr = rr * 16 + ty;
        bf16x4 ohi, olo;
#pragma unroll
        for (int j = 0; j < 4; ++j) {
            float x = lds[tx*4+j][nr];
            __bf16 h = (__bf16)x;
            ohi[j] = h;
            olo[j] = (__bf16)(x - (float)h);
        }
        *(bf16x4*)(dhi + (size_t)nr * 2048 + tx * 4) = ohi;
        *(bf16x4*)(dlo + (size_t)nr * 2048 + tx * 4) = olo;
    }
}

// plain f32 -> bf16 (hi only), 8 elems/thread, exact grid
__global__ __launch_bounds__(256) void k_cvt(const float* __restrict__ in,
                                             __bf16* __restrict__ out) {
    size_t i = ((size_t)blockIdx.x * 256 + threadIdx.x) * 8;
    f32x4 v0 = *(const f32x4*)(in + i);
    f32x4 v1 = *(const f32x4*)(in + i + 4);
    bf16x8 o;
    o[0]=(__bf16)v0[0]; o[1]=(__bf16)v0[1]; o[2]=(__bf16)v0[2]; o[3]=(__bf16)v0[3];
    o[4]=(__bf16)v1[0]; o[5]=(__bf16)v1[1]; o[6]=(__bf16)v1[2]; o[7]=(__bf16)v1[3];
    *(bf16x8*)(out + i) = o;
}

// embedding gather -> time-major [t*32+b][1024] hi/lo bf16
__global__ __launch_bounds__(256) void k_embed(const int* __restrict__ idx,
                                               const float* __restrict__ emb,
                                               __bf16* __restrict__ xhi,
                                               __bf16* __restrict__ xlo) {
    const int row = blockIdx.x;            // t*32 + b
    const int t = row >> 5, b = row & 31;
    const int id = idx[b * SEQ + t];
    const int tid = threadIdx.x;
    f32x4 v = *(const f32x4*)(emb + (size_t)id * RNN + tid * 4);
    bf16x4 hi, lo;
#pragma unroll
    for (int j = 0; j < 4; ++j) {
        __bf16 h = (__bf16)v[j];
        hi[j] = h; lo[j] = (__bf16)(v[j] - (float)h);
    }
    *(bf16x4*)(xhi + (size_t)row * RNN + tid * 4) = hi;
    *(bf16x4*)(xlo + (size_t)row * RNN + tid * 4) = lo;
}

// ---------------------------------------------------------------------------
// zx[4096][4096] = X @ Wx + bias (layer 0 only), 3-term split bf16 MFMA.
__global__ __launch_bounds__(256) void k_xgemm(const __bf16* __restrict__ xhi,
                                               const __bf16* __restrict__ xlo,
                                               const __bf16* __restrict__ Wt, // layer base
                                               const float* __restrict__ bias,
                                               float* __restrict__ zx) {
    __shared__ __bf16 Aim[2][4][4][512];   // 32 KB (hi/lo planes)
    __shared__ __bf16 Bim[2][4][4][512];   // 32 KB
    const int tid = threadIdx.x;
    const int lane = tid & 63, w = tid >> 6;
    const int g = lane >> 4, q = lane & 15;
    const int n0 = blockIdx.x * 64, m0 = blockIdx.y * 64;
    f32x4 acc[4] = {{0,0,0,0},{0,0,0,0},{0,0,0,0},{0,0,0,0}};

    for (int ch = 0; ch < 8; ++ch) {       // 8 chunks of K=128
        __syncthreads();                   // previous compute done
        for (int i = tid; i < 2048; i += 256) {   // stage A (both planes)
            int pl = i >> 10, rem = i & 1023;
            int r = rem >> 4, cc = rem & 15;
            const __bf16* s = (pl ? xlo : xhi) + (size_t)(m0 + r) * RNN + ch * 128 + cc * 8;
            bf16x8 v = *(const bf16x8*)s;
            *(bf16x8*)&Aim[pl][r >> 4][cc >> 2][(((cc & 3) << 4) + (r & 15)) << 3] = v;
        }
        for (int i = tid; i < 2048; i += 256) {   // stage B (both planes)
            int pl = i >> 10, rem = i & 1023;
            int r = rem >> 4, cc = rem & 15;
            const __bf16* s = Wt + ((size_t)(pl ? 4096 : 0) + n0 + r) * 2048 + ch * 128 + cc * 8;
            bf16x8 v = *(const bf16x8*)s;
            *(bf16x8*)&Bim[pl][r >> 4][cc >> 2][(((cc & 3) << 4) + (r & 15)) << 3] = v;
        }
        __syncthreads();
#pragma unroll
        for (int kc = 0; kc < 4; ++kc) {
            bf16x8 bhf = *(const bf16x8*)&Bim[0][w][kc][lane << 3];
            bf16x8 blf = *(const bf16x8*)&Bim[1][w][kc][lane << 3];
#pragma unroll
            for (int mt = 0; mt < 4; ++mt) {
                bf16x8 ahf = *(const bf16x8*)&Aim[0][mt][kc][lane << 3];
                bf16x8 alf = *(const bf16x8*)&Aim[1][mt][kc][lane << 3];
                acc[mt] = __builtin_amdgcn_mfma_f32_16x16x32_bf16(ahf, bhf, acc[mt], 0, 0, 0);
                acc[mt] = __builtin_amdgcn_mfma_f32_16x16x32_bf16(alf, bhf, acc[mt], 0, 0, 0);
                acc[mt] = __builtin_amdgcn_mfma_f32_16x16x32_bf16(ahf, blf, acc[mt], 0, 0, 0);
            }
        }
    }
    const int n = n0 + w * 16 + q;
    const float bv = bias[n];
#pragma unroll
    for (int mt = 0; mt < 4; ++mt)
#pragma unroll
        for (int r = 0; r < 4; ++r) {
            int m = m0 + mt * 16 + g * 4 + r;
            zx[(size_t)m * 4096 + n] = acc[mt][r] + bv;
        }
}

// ---------------------------------------------------------------------------
// Producer arrival: drain own sc1 stores, block-wide, then post slot.
__device__ __forceinline__ void arrive(unsigned* slots, int bk, int tid, unsigned gen) {
    drain_vm();
    __syncthreads();
    if (tid == 0) ast(&slots[bk * AR_STRIDE], gen);
}

// ---------------------------------------------------------------------------
// Persistent per-layer recurrence + helper x-GEMM.
// Blocks 0..127: recurrence; fine-grained sync (consumers poll only their
// producers' slots, then load immediately). Blocks 128..255 (l<3): helpers
// computing zx(l+1)[t] after h(l)[t] is published (poll bar2 coarsely).
__global__ __launch_bounds__(256, 1) void k_rnn(
        const __bf16* __restrict__ Wl,    // layer base [2][4096][2048]
        float* __restrict__ zx,           // [SEQ*32][4096] (bias folded)
        float* __restrict__ z,            // [32][4096] scratch (sc1 only)
        __bf16* __restrict__ xhi, __bf16* __restrict__ xlo,  // [SEQ*32][1024]
        const float* __restrict__ g5, const float* __restrict__ b5,
        unsigned* bar, unsigned gen0,
        const __bf16* __restrict__ Wn,    // next-layer base (helpers)
        const float* __restrict__ bias_n) // next-layer bias (helpers)
{
    __shared__ __bf16 wl[2][32768];       // 128 KB weight slice (lane-read order)
    __shared__ f32x4 pred[2][2][64];      // 4 KB partial accs [mt][nt][lane]
    __shared__ float red[4][8];
    unsigned* bar2 = bar + GBLK * AR_STRIDE;

    const int bk = blockIdx.x, tid = threadIdx.x;
    const int lane = tid & 63, w = tid >> 6;
    const int q = lane & 15, g = lane >> 4;
    const int mt = w & 1, kh = w >> 1;
    const int zr0  = (mt << 4) + (g << 2);
    const int hrow = (mt << 4) + q;       // h row this lane reads

    // ======================= helper blocks (128..255) =======================
    if (bk >= GBLK) {
        const int hk = bk - GBLK;
        const int ncolh = (hk << 5) + q;
        {
            const __bf16* hi_src = Wn + ((size_t)(hk << 5)) * 2048;
            const __bf16* lo_src = Wn + ((size_t)(4096 + (hk << 5))) * 2048;
            for (int i = tid; i < 8192; i += 256) {
                int pl = i >> 12, rem = i & 4095;
                int r = rem >> 7, cc = rem & 127;
                const __bf16* s = (pl ? lo_src : hi_src) + (size_t)r * 2048 + cc * 8;
                bf16x8 v = *(const bf16x8*)s;
                int rnt = r >> 4, rq = r & 15, kc = cc >> 2, rg = cc & 3;
                *(bf16x8*)&wl[pl][((rnt * 32 + kc) << 9) + ((rg * 16 + rq) << 3)] = v;
            }
        }
        float bv0 = 0.f, bv1 = 0.f;
        if (kh == 0) { bv0 = bias_n[ncolh]; bv1 = bias_n[ncolh + 16]; }
        __syncthreads();
        const __bf16* hb0 = &wl[0][0]        + (lane << 3);
        const __bf16* lb0 = &wl[1][0]        + (lane << 3);
        const __bf16* hb1 = &wl[0][32 << 9]  + (lane << 3);
        const __bf16* lb1 = &wl[1][32 << 9]  + (lane << 3);

        for (int t = 0; t < SEQ; ++t) {
            const unsigned gen = gen0 + (unsigned)t + 1u;
            // per-lane poll: only the gate slot for this lane's h row
            while (ald(&bar2[hrow * AR_STRIDE]) < gen) __builtin_amdgcn_s_sleep(1);
            const __bf16* ah = xhi + ((size_t)t * BATCH + hrow) * RNN;
            const __bf16* al = xlo + ((size_t)t * BATCH + hrow) * RNN;
            f32x4 a00={0,0,0,0}, a01={0,0,0,0}, a02={0,0,0,0};
            f32x4 a10={0,0,0,0}, a11={0,0,0,0}, a12={0,0,0,0};
            const int k0 = kh << 4;
#pragma unroll 4
            for (int kc = k0; kc < k0 + 16; ++kc) {
                bf16x8 ahf = *(const bf16x8*)(ah + (kc << 5) + (g << 3));
                bf16x8 alf = *(const bf16x8*)(al + (kc << 5) + (g << 3));
                bf16x8 b0h = *(const bf16x8*)(hb0 + (kc << 9));
                bf16x8 b0l = *(const bf16x8*)(lb0 + (kc << 9));
                bf16x8 b1h = *(const bf16x8*)(hb1 + (kc << 9));
                bf16x8 b1l = *(const bf16x8*)(lb1 + (kc << 9));
                a00 = __builtin_amdgcn_mfma_f32_16x16x32_bf16(ahf, b0h, a00, 0, 0, 0);
                a01 = __builtin_amdgcn_mfma_f32_16x16x32_bf16(alf, b0h, a01, 0, 0, 0);
                a02 = __builtin_amdgcn_mfma_f32_16x16x32_bf16(ahf, b0l, a02, 0, 0, 0);
                a10 = __builtin_amdgcn_mfma_f32_16x16x32_bf16(ahf, b1h, a10, 0, 0, 0);
                a11 = __builtin_amdgcn_mfma_f32_16x16x32_bf16(alf, b1h, a11, 0, 0, 0);
                a12 = __builtin_amdgcn_mfma_f32_16x16x32_bf16(ahf, b1l, a12, 0, 0, 0);
            }
            f32x4 s0, s1;
#pragma unroll
            for (int j = 0; j < 4; ++j) {
                s0[j] = a00[j] + a01[j] + a02[j];
                s1[j] = a10[j] + a11[j] + a12[j];
            }
            if (kh == 1) { pred[mt][0][lane] = s0; pred[mt][1][lane] = s1; }
            __syncthreads();
            if (kh == 0) {
                f32x4 p0 = pred[mt][0][lane], p1 = pred[mt][1][lane];
#pragma unroll
                for (int r = 0; r < 4; ++r) {
                    zx[((size_t)t * BATCH + zr0 + r) * 4096 + ncolh]      = s0[r] + p0[r] + bv0;
                    zx[((size_t)t * BATCH + zr0 + r) * 4096 + ncolh + 16] = s1[r] + p1[r] + bv1;
                }
            }
            __syncthreads();   // pred WAR across t
        }
        return;
    }

    // ======================= recurrence blocks (0..127) =====================
    const int ncol = (bk << 5) + q;       // nt=0 col; nt=1 at +16

    // ---- stage Wh hi+lo into LDS (lane-read order) ----
    {
        const __bf16* hi_src = Wl + ((size_t)(bk << 5)) * 2048 + RNN;
        const __bf16* lo_src = Wl + ((size_t)(4096 + (bk << 5))) * 2048 + RNN;
        for (int i = tid; i < 8192; i += 256) {
            int pl = i >> 12, rem = i & 4095;
            int r = rem >> 7, cc = rem & 127;
            const __bf16* s = (pl ? lo_src : hi_src) + (size_t)r * 2048 + cc * 8;
            bf16x8 v = *(const bf16x8*)s;
            int rnt = r >> 4, rq = r & 15, kc = cc >> 2, rg = cc & 3;
            *(bf16x8*)&wl[pl][((rnt * 32 + kc) << 9) + ((rg * 16 + rq) << 3)] = v;
        }
    }

    // ---- gate-block constants (blocks 0..31) ----
    const bool is_gate = (bk < BATCH);
    f32x4 gi, bi, gj, bj, gf, bfv, go, bo, g4, b4;
    if (is_gate) {
        gi = *(const f32x4*)(g5 + 0*RNN + tid*4); bi = *(const f32x4*)(b5 + 0*RNN + tid*4);
        gj = *(const f32x4*)(g5 + 1*RNN + tid*4); bj = *(const f32x4*)(b5 + 1*RNN + tid*4);
        gf = *(const f32x4*)(g5 + 2*RNN + tid*4); bfv= *(const f32x4*)(b5 + 2*RNN + tid*4);
        go = *(const f32x4*)(g5 + 3*RNN + tid*4); bo = *(const f32x4*)(b5 + 3*RNN + tid*4);
        g4 = *(const f32x4*)(g5 + 4*RNN + tid*4); b4 = *(const f32x4*)(b5 + 4*RNN + tid*4);
    }
    const float inv = 1.f / (float)RNN;
    f32x4 creg = {0.f, 0.f, 0.f, 0.f};    // cell state lives in registers
    __syncthreads();   // LDS staged

    const __bf16* bh0 = &wl[0][0]        + (lane << 3);   // nt=0 hi (+kc<<9)
    const __bf16* bl0 = &wl[1][0]        + (lane << 3);   // nt=0 lo
    const __bf16* bh1 = &wl[0][32 << 9]  + (lane << 3);   // nt=1 hi
    const __bf16* bl1 = &wl[1][32 << 9]  + (lane << 3);   // nt=1 lo

    // gate phase-B producer slots: thread tid reads z cols tid*4 (+1024*s),
    // produced by col-blocks pb+{0,32,64,96}
    const int pb = tid >> 3;

    // zx prefetch (t = 0), kh0 waves only (they finalize z)
    float zv0[4], zv1[4];
    if (kh == 0) {
        const float* zxp = zx + (size_t)zr0 * 4096 + ncol;
#pragma unroll
        for (int r = 0; r < 4; ++r) {
            zv0[r] = zxp[(size_t)r * 4096];
            zv1[r] = zxp[(size_t)r * 4096 + 16];
        }
    }

    for (int t = 0; t < SEQ; ++t) {
        const unsigned gen = gen0 + (unsigned)t + 1u;
        // ---- phase A: z_t = zx[t] + h_{t-1} @ Wh (K-split across waves) ----
        f32x4 a00={0,0,0,0}, a01={0,0,0,0}, a02={0,0,0,0};
        f32x4 a10={0,0,0,0}, a11={0,0,0,0}, a12={0,0,0,0};
        if (t > 0) {
            // fine-grained: wait only for this lane's h-row producer (step t-1)
            while (ald(&bar2[hrow * AR_STRIDE]) < gen - 1u) __builtin_amdgcn_s_sleep(1);
            const __bf16* ah = xhi + ((size_t)(t - 1) * BATCH + hrow) * RNN;
            const __bf16* al = xlo + ((size_t)(t - 1) * BATCH + hrow) * RNN;
            const int k0 = kh << 4;
#pragma unroll 4
            for (int kc = k0; kc < k0 + 16; ++kc) {
                bf16x8 ahf = *(const bf16x8*)(ah + (kc << 5) + (g << 3));   // normal 16B
                bf16x8 alf = *(const bf16x8*)(al + (kc << 5) + (g << 3));
                bf16x8 b0h = *(const bf16x8*)(bh0 + (kc << 9));
                bf16x8 b0l = *(const bf16x8*)(bl0 + (kc << 9));
                bf16x8 b1h = *(const bf16x8*)(bh1 + (kc << 9));
                bf16x8 b1l = *(const bf16x8*)(bl1 + (kc << 9));
                a00 = __builtin_amdgcn_mfma_f32_16x16x32_bf16(ahf, b0h, a00, 0, 0, 0);
                a01 = __builtin_amdgcn_mfma_f32_16x16x32_bf16(alf, b0h, a01, 0, 0, 0);
                a02 = __builtin_amdgcn_mfma_f32_16x16x32_bf16(ahf, b0l, a02, 0, 0, 0);
                a10 = __builtin_amdgcn_mfma_f32_16x16x32_bf16(ahf, b1h, a10, 0, 0, 0);
                a11 = __builtin_amdgcn_mfma_f32_16x16x32_bf16(alf, b1h, a11, 0, 0, 0);
                a12 = __builtin_amdgcn_mfma_f32_16x16x32_bf16(ahf, b1l, a12, 0, 0, 0);
            }
        }
        {
            f32x4 s0, s1;
#pragma unroll
            for (int j = 0; j < 4; ++j) {
                s0[j] = a00[j] + a01[j] + a02[j];
                s1[j] = a10[j] + a11[j] + a12[j];
            }
            if (kh == 1) { pred[mt][0][lane] = s0; pred[mt][1][lane] = s1; }
            __syncthreads();   // pred ready; also: all lanes' h-polls passed
                               // => all 32 gates drained z[t-1] reads (z-WAR)
            if (kh == 0) {
                f32x4 p0 = pred[mt][0][lane], p1 = pred[mt][1][lane];
#pragma unroll
                for (int r = 0; r < 4; ++r) {
                    astf(&z[(size_t)(zr0 + r) * 4096 + ncol],      s0[r] + p0[r] + zv0[r]);
                    astf(&z[(size_t)(zr0 + r) * 4096 + ncol + 16], s1[r] + p1[r] + zv1[r]);
                }
            }
        }
        arrive(bar, bk, tid, gen);    // post: this block's z slice visible

        // ---- prefetch zx for t+1 (hides under phase B) ----
        if (kh == 0 && t + 1 < SEQ) {
            const float* zxp = zx + ((size_t)(t + 1) * BATCH + zr0) * 4096 + ncol;
#pragma unroll
            for (int r = 0; r < 4; ++r) {
                zv0[r] = zxp[(size_t)r * 4096];
                zv1[r] = zxp[(size_t)r * 4096 + 16];
            }
        }

        // ---- phase B: gates (blocks 0..31), fine-grained z consumption ----
        if (is_gate) {
            const int b = bk;
            const float* zrow = z + (size_t)b * 4096 + tid * 4;
            auto ld4 = [&](const float* p) -> f32x4 {
                U128F x;
                x.u[0] = ald64((const unsigned long long*)p);
                x.u[1] = ald64((const unsigned long long*)p + 1);
                return x.f;
            };
            // poll only the 4 producer col-blocks of this thread's columns
            while (ald(&bar[(pb      ) * AR_STRIDE]) < gen) __builtin_amdgcn_s_sleep(1);
            f32x4 zi = ld4(zrow);
            while (ald(&bar[(pb + 32) * AR_STRIDE]) < gen) __builtin_amdgcn_s_sleep(1);
            f32x4 zjv = ld4(zrow + 1024);
            while (ald(&bar[(pb + 64) * AR_STRIDE]) < gen) __builtin_amdgcn_s_sleep(1);
            f32x4 zfv = ld4(zrow + 2048);
            while (ald(&bar[(pb + 96) * AR_STRIDE]) < gen) __builtin_amdgcn_s_sleep(1);
            f32x4 zov = ld4(zrow + 3072);
            float s[8];
            s[0] = zi[0]+zi[1]+zi[2]+zi[3];
            s[1] = zi[0]*zi[0]+zi[1]*zi[1]+zi[2]*zi[2]+zi[3]*zi[3];
            s[2] = zjv[0]+zjv[1]+zjv[2]+zjv[3];
            s[3] = zjv[0]*zjv[0]+zjv[1]*zjv[1]+zjv[2]*zjv[2]+zjv[3]*zjv[3];
            s[4] = zfv[0]+zfv[1]+zfv[2]+zfv[3];
            s[5] = zfv[0]*zfv[0]+zfv[1]*zfv[1]+zfv[2]*zfv[2]+zfv[3]*zfv[3];
            s[6] = zov[0]+zov[1]+zov[2]+zov[3];
            s[7] = zov[0]*zov[0]+zov[1]*zov[1]+zov[2]*zov[2]+zov[3]*zov[3];
#pragma unroll
            for (int o = 32; o; o >>= 1)
#pragma unroll
                for (int i = 0; i < 8; ++i) s[i] += __shfl_xor(s[i], o);
            if (lane == 0) {
#pragma unroll
                for (int i = 0; i < 8; ++i) red[w][i] = s[i];
            }
            __syncthreads();
            float tot[8];
#pragma unroll
            for (int i = 0; i < 8; ++i) tot[i] = red[0][i]+red[1][i]+red[2][i]+red[3][i];

            float mi = tot[0]*inv, ri = rsqrtf(tot[1]*inv - mi*mi + 1e-5f);
            float mj = tot[2]*inv, rj = rsqrtf(tot[3]*inv - mj*mj + 1e-5f);
            float mf = tot[4]*inv, rf = rsqrtf(tot[5]*inv - mf*mf + 1e-5f);
            float mo = tot[6]*inv, ro = rsqrtf(tot[7]*inv - mo*mo + 1e-5f);

            f32x4 onrm;
            float cs = 0.f, cq = 0.f;
#pragma unroll
            for (int j = 0; j < 4; ++j) {
                float iv = (zi[j]-mi)*ri*gi[j] + bi[j];
                float jv = (zjv[j]-mj)*rj*gj[j] + bj[j];
                float fv = (zfv[j]-mf)*rf*gf[j] + bfv[j];
                float ov = (zov[j]-mo)*ro*go[j] + bo[j];
                float cc = creg[j] * sigm(fv + 1.0f) + sigm(iv) * tanhf(jv);
                creg[j] = cc; onrm[j] = ov;
                cs += cc; cq += cc*cc;
            }

            __syncthreads();   // protect red[] reuse
            float s2a = cs, s2b = cq;
#pragma unroll
            for (int o = 32; o; o >>= 1) { s2a += __shfl_xor(s2a, o); s2b += __shfl_xor(s2b, o); }
            if (lane == 0) { red[w][0] = s2a; red[w][1] = s2b; }
            __syncthreads();
            float mc = (red[0][0]+red[1][0]+red[2][0]+red[3][0]) * inv;
            float vc = (red[0][1]+red[1][1]+red[2][1]+red[3][1]) * inv - mc*mc;
            float rc = rsqrtf(vc + 1e-5f);

            bf16x4 hh, hl;
#pragma unroll
            for (int j = 0; j < 4; ++j) {
                float cn = (creg[j]-mc)*rc*g4[j] + b4[j];
                float h = tanhf(cn) * sigm(onrm[j]);
                __bf16 a = (__bf16)h;
                hh[j] = a; hl[j] = (__bf16)(h - (float)a);
            }
            U64B ph, pl;
            ph.v = hh; pl.v = hl;
            // single h store: time-indexed x buffers (sc1 -> coherence point)
            ast64((unsigned long long*)&xhi[((size_t)t * BATCH + b) * RNN + tid * 4], ph.u);
            ast64((unsigned long long*)&xlo[((size_t)t * BATCH + b) * RNN + tid * 4], pl.u);
            arrive(bar2, bk, tid, gen);   // post: h row b visible
        }
        // non-gate blocks: no wait here; they poll per-lane at phase A(t+1)
    }
}

// ---------------------------------------------------------------------------
// k_proj: logits[m][v] = sum_k h[m][k]*smw[v][k] + smb[v], m = b*128+t.
// 128x128 tile, BK=32, double-buffered reg-staging, 1 sync per K-step.
__global__ __launch_bounds__(256) void k_proj(const __bf16* __restrict__ xs,
                                              const __bf16* __restrict__ wv,
                                              const float* __restrict__ sb,
                                              float* __restrict__ out) {
    __shared__ __bf16 Asm[2][8][512];      // 16 KB (2 bufs x 8 subtiles x 1KB)
    __shared__ __bf16 Bsm[2][8][512];      // 16 KB
    const int tid = threadIdx.x;
    const int lane = tid & 63, w = tid >> 6;
    const int wm = w & 1, wn = w >> 1;     // wave quadrant: 64(m) x 64(n)
    const int bid = blockIdx.x;            // 8000 blocks (250 n x 32 m)
    const int swz = (bid & 7) * 1000 + (bid >> 3);   // XCD-bijective chunks
    const int m0 = (swz & 31) << 7;        // m fastest (32 m-blocks)
    const int n0 = (swz >> 5) << 7;        // 250 n-blocks
    const int mb = m0 >> 7;

    const int lr = lane >> 2, cc4 = lane & 3;
    const __bf16* asrc[2];
    const __bf16* bsrc[2];
#pragma unroll
    for (int p = 0; p < 2; ++p) {
        int st = p * 4 + w;
        asrc[p] = xs + (size_t)((st * 16 + lr) * 32 + mb) * RNN + cc4 * 8;
        bsrc[p] = wv + (size_t)(n0 + st * 16 + lr) * RNN + cc4 * 8;
    }
    const int gidx = cc4 * 16 + lr;        // write granule (bijective per wave)

    f32x4 acc[4][4];
#pragma unroll
    for (int i = 0; i < 4; ++i)
#pragma unroll
        for (int j = 0; j < 4; ++j) acc[i][j] = (f32x4){0.f, 0.f, 0.f, 0.f};

    bf16x8 ar[2], br[2];
#pragma unroll
    for (int p = 0; p < 2; ++p) {
        ar[p] = *(const bf16x8*)(asrc[p]);
        br[p] = *(const bf16x8*)(bsrc[p]);
    }
#pragma unroll
    for (int p = 0; p < 2; ++p) {
        int st = p * 4 + w;
        *(bf16x8*)&Asm[0][st][gidx * 8] = ar[p];
        *(bf16x8*)&Bsm[0][st][gidx * 8] = br[p];
    }
    __syncthreads();

    for (int s = 0; s < 32; ++s) {         // K-steps of 32
        const int buf = s & 1;
        if (s + 1 < 32) {
            const int k0 = (s + 1) * 32;
#pragma unroll
            for (int p = 0; p < 2; ++p) {
                ar[p] = *(const bf16x8*)(asrc[p] + k0);
                br[p] = *(const bf16x8*)(bsrc[p] + k0);
            }
        }
        bf16x8 af[4], bfr[4];
#pragma unroll
        for (int i = 0; i < 4; ++i) {
            af[i]  = *(const bf16x8*)&Asm[buf][wm * 4 + i][lane * 8];
            bfr[i] = *(const bf16x8*)&Bsm[buf][wn * 4 + i][lane * 8];
        }
#pragma unroll
        for (int mi = 0; mi < 4; ++mi)
#pragma unroll
            for (int ni = 0; ni < 4; ++ni)
                acc[mi][ni] = __builtin_amdgcn_mfma_f32_16x16x32_bf16(
                    af[mi], bfr[ni], acc[mi][ni], 0, 0, 0);
        if (s + 1 < 32) {
#pragma unroll
            for (int p = 0; p < 2; ++p) {
                int st = p * 4 + w;
                *(bf16x8*)&Asm[buf ^ 1][st][gidx * 8] = ar[p];
                *(bf16x8*)&Bsm[buf ^ 1][st][gidx * 8] = br[p];
            }
        }
        __syncthreads();
    }

    const int q = lane & 15, g = lane >> 4;
#pragma unroll
    for (int ni = 0; ni < 4; ++ni) {
        const int n = n0 + wn * 64 + ni * 16 + q;
        const float bv = sb[n];
#pragma unroll
        for (int mi = 0; mi < 4; ++mi) {
            const int mbase = m0 + wm * 64 + mi * 16 + g * 4;
#pragma unroll
            for (int r = 0; r < 4; ++r)
                __builtin_nontemporal_store(acc[mi][ni][r] + bv,
                                            &out[(size_t)(mbase + r) * VOCAB + n]);
        }
    }
}

// ---------------------------------------------------------------------------
extern "C" void kernel_launch(void* const* d_in, const int* in_sizes, int n_in,
                              void* d_out, int out_size, void* d_ws, size_t ws_size,
                              hipStream_t stream) {
    const int*   input = (const int*)  d_in[0];
    const float* emb   = (const float*)d_in[1];
    const float* W     = (const float*)d_in[2];
    const float* bias  = (const float*)d_in[3];
    const float* ln_g  = (const float*)d_in[4];
    const float* ln_b  = (const float*)d_in[5];
    const float* smw   = (const float*)d_in[6];
    const float* smb   = (const float*)d_in[7];
    float* out = (float*)d_out;

    char* p = (char*)d_ws;
    auto alloc = [&](size_t bytes) { char* r = p; p += (bytes + 255) & ~(size_t)255; return r; };
    __bf16* Wt   = (__bf16*)alloc((size_t)NLAY * 2 * 4096 * 2048 * 2); // 134.2 MB
    __bf16* smwb = (__bf16*)alloc((size_t)VOCAB * RNN * 2);            // 65.5 MB
    __bf16* xhi  = (__bf16*)alloc((size_t)SEQ * BATCH * RNN * 2);      // 8.4 MB
    __bf16* xlo  = (__bf16*)alloc((size_t)SEQ * BATCH * RNN * 2);      // 8.4 MB
    float*  zx   = (float*) alloc((size_t)SEQ * BATCH * 4096 * 4);     // 67.1 MB
    float*  z    = (float*) alloc((size_t)BATCH * 4096 * 4);           // 512 KB
    unsigned* bar= (unsigned*)alloc(2 * GBLK * AR_STRIDE * 4);         // 2 slot arrays

    hipMemsetAsync(bar, 0, 2 * GBLK * AR_STRIDE * 4, stream);

    k_cvt_w<<<dim3(64, 32, NLAY), 256, 0, stream>>>(W, Wt);
    k_cvt<<<(VOCAB * RNN) / (8 * 256), 256, 0, stream>>>(smw, smwb);
    k_embed<<<SEQ * BATCH, 256, 0, stream>>>(input, emb, xhi, xlo);

    // zx for layer 0 (all x available upfront)
    k_xgemm<<<dim3(64, 64), 256, 0, stream>>>(xhi, xlo, Wt, bias, zx);

    for (int l = 0; l < NLAY; ++l) {
        const __bf16* Wl  = Wt + (size_t)l * 2 * 4096 * 2048;
        const float*  gl  = ln_g + (size_t)l * 5 * RNN;
        const float*  bbl = ln_b + (size_t)l * 5 * RNN;
        const int lnext = (l + 1 < NLAY) ? (l + 1) : l;   // dummy for l=3
        const __bf16* Wn  = Wt + (size_t)lnext * 2 * 4096 * 2048;
        const float*  bn  = bias + (size_t)lnext * 4096;
        {
            const __bf16* Wl_ = Wl;
            float* zx_ = zx;
            float* z_ = z;
            __bf16 *xhi_ = xhi, *xlo_ = xlo;
            const float *gl_ = gl, *bbl_ = bbl;
            unsigned* bar_ = bar;
            unsigned gen0 = (unsigned)(l * SEQ);
            const __bf16* Wn_ = Wn;
            const float* bn_ = bn;
            void* args[] = {(void*)&Wl_, (void*)&zx_, (void*)&z_,
                            (void*)&xhi_, (void*)&xlo_, (void*)&gl_, (void*)&bbl_,
                            (void*)&bar_, (void*)&gen0, (void*)&Wn_, (void*)&bn_};
            // l<3: 256 blocks (128 recurrence + 128 zx helpers on idle CUs)
            int nblk = (l + 1 < NLAY) ? 2 * GBLK : GBLK;
            hipLaunchCooperativeKernel((const void*)k_rnn,
                                       dim3(nblk), dim3(256), args, 0, stream);
        }
    }
    // final layer output (bf16 hi) lives in xhi (time-major)
    k_proj<<<dim3(8000), 256, 0, stream>>>(xhi, smwb, smb, out);
}

// Round 14
// 5746.468 us; speedup vs baseline: 1.0964x; 1.0964x over previous
//
#include <hip/hip_runtime.h>
#include <hip/hip_bf16.h>

// CharRNN: embed -> 4x (LayerNorm-LSTM over T=128) -> projection to vocab.
// Round 13: revert round-12's fine-grained sync (regressed; coarse flat
// barrier restored). NEW: the projection is folded into the l=3 k_rnn launch
// as 128 proj-helper blocks on the otherwise-idle CUs: each polls bar2 gate
// slots (time-progressive) and streams 128x128 logit tiles as layer-3 h
// becomes available. Separate k_proj dispatch eliminated (~500us serial).

typedef __bf16 bf16x8 __attribute__((ext_vector_type(8)));
typedef __bf16 bf16x4 __attribute__((ext_vector_type(4)));
typedef float  f32x4  __attribute__((ext_vector_type(4)));

#define VOCAB 32000
#define BATCH 32
#define SEQ   128
#define RNN   1024
#define NLAY  4
#define GBLK  128
#define AR_STRIDE 16            // dwords between arrival slots (64 B)
#define NTILES_N 250            // 32000 / 128
#define NTILES_T 32             // 4096 / 128
#define NTILES  (NTILES_N * NTILES_T)

__device__ __forceinline__ float sigm(float x) { return 1.f / (1.f + __expf(-x)); }

// ---- agent-scope relaxed atomics (sc1: coherence-point, bypass stale L2) ----
__device__ __forceinline__ unsigned ald(const unsigned* p) {
    return __hip_atomic_load(p, __ATOMIC_RELAXED, __HIP_MEMORY_SCOPE_AGENT);
}
__device__ __forceinline__ void ast(unsigned* p, unsigned v) {
    __hip_atomic_store(p, v, __ATOMIC_RELAXED, __HIP_MEMORY_SCOPE_AGENT);
}
__device__ __forceinline__ unsigned long long ald64(const unsigned long long* p) {
    return __hip_atomic_load(p, __ATOMIC_RELAXED, __HIP_MEMORY_SCOPE_AGENT);
}
__device__ __forceinline__ void ast64(unsigned long long* p, unsigned long long v) {
    __hip_atomic_store(p, v, __ATOMIC_RELAXED, __HIP_MEMORY_SCOPE_AGENT);
}
__device__ __forceinline__ void astf(float* p, float v) {
    __hip_atomic_store(p, v, __ATOMIC_RELAXED, __HIP_MEMORY_SCOPE_AGENT);
}
__device__ __forceinline__ void drain_vm() {
    asm volatile("s_waitcnt vmcnt(0)" ::: "memory");
}

typedef union { unsigned long long u[2]; f32x4 f; }  U128F;
typedef union { unsigned long long u; bf16x4 v; }    U64B;

// ---------------------------------------------------------------------------
// W [L][2048][4096] f32 -> Wt [L][2 planes (hi,lo)][4096][2048] bf16,
// transposed to [n][k]. k 0..1023 = x-part (Wx), k 1024..2047 = h-part (Wh).
__global__ __launch_bounds__(256) void k_cvt_w(const float* __restrict__ W,
                                               __bf16* __restrict__ Wt) {
    __shared__ float lds[64][65];
    const int tid = threadIdx.x, tx = tid & 15, ty = tid >> 4;
    const int n0 = blockIdx.x * 64, k0 = blockIdx.y * 64;
    const size_t l = blockIdx.z;
    const float* src = W + (l * 2048 + (size_t)k0) * 4096 + n0;
#pragma unroll
    for (int rr = 0; rr < 4; ++rr) {
        int kr = rr * 16 + ty;
        f32x4 v = *(const f32x4*)(src + (size_t)kr * 4096 + tx * 4);
        lds[kr][tx*4+0] = v[0]; lds[kr][tx*4+1] = v[1];
        lds[kr][tx*4+2] = v[2]; lds[kr][tx*4+3] = v[3];
    }
    __syncthreads();
    __bf16* dhi = Wt + ((l * 2 + 0) * 4096 + (size_t)n0) * 2048 + k0;
    __bf16* dlo = Wt + ((l * 2 + 1) * 4096 + (size_t)n0) * 2048 + k0;
#pragma unroll
    for (int rr = 0; rr < 4; ++rr) {
        int nr = rr * 16 + ty;
        bf16x4 ohi, olo;
#pragma unroll
        for (int j = 0; j < 4; ++j) {
            float x = lds[tx*4+j][nr];
            __bf16 h = (__bf16)x;
            ohi[j] = h;
            olo[j] = (__bf16)(x - (float)h);
        }
        *(bf16x4*)(dhi + (size_t)nr * 2048 + tx * 4) = ohi;
        *(bf16x4*)(dlo + (size_t)nr * 2048 + tx * 4) = olo;
    }
}

// plain f32 -> bf16 (hi only), 8 elems/thread, exact grid
__global__ __launch_bounds__(256) void k_cvt(const float* __restrict__ in,
                                             __bf16* __restrict__ out) {
    size_t i = ((size_t)blockIdx.x * 256 + threadIdx.x) * 8;
    f32x4 v0 = *(const f32x4*)(in + i);
    f32x4 v1 = *(const f32x4*)(in + i + 4);
    bf16x8 o;
    o[0]=(__bf16)v0[0]; o[1]=(__bf16)v0[1]; o[2]=(__bf16)v0[2]; o[3]=(__bf16)v0[3];
    o[4]=(__bf16)v1[0]; o[5]=(__bf16)v1[1]; o[6]=(__bf16)v1[2]; o[7]=(__bf16)v1[3];
    *(bf16x8*)(out + i) = o;
}

// embedding gather -> time-major [t*32+b][1024] hi/lo bf16
__global__ __launch_bounds__(256) void k_embed(const int* __restrict__ idx,
                                               const float* __restrict__ emb,
                                               __bf16* __restrict__ xhi,
                                               __bf16* __restrict__ xlo) {
    const int row = blockIdx.x;            // t*32 + b
    const int t = row >> 5, b = row & 31;
    const int id = idx[b * SEQ + t];
    const int tid = threadIdx.x;
    f32x4 v = *(const f32x4*)(emb + (size_t)id * RNN + tid * 4);
    bf16x4 hi, lo;
#pragma unroll
    for (int j = 0; j < 4; ++j) {
        __bf16 h = (__bf16)v[j];
        hi[j] = h; lo[j] = (__bf16)(v[j] - (float)h);
    }
    *(bf16x4*)(xhi + (size_t)row * RNN + tid * 4) = hi;
    *(bf16x4*)(xlo + (size_t)row * RNN + tid * 4) = lo;
}

// ---------------------------------------------------------------------------
// zx[4096][4096] = X @ Wx + bias (layer 0 only), 3-term split bf16 MFMA.
__global__ __launch_bounds__(256) void k_xgemm(const __bf16* __restrict__ xhi,
                                               const __bf16* __restrict__ xlo,
                                               const __bf16* __restrict__ Wt, // layer base
                                               const float* __restrict__ bias,
                                               float* __restrict__ zx) {
    __shared__ __bf16 Aim[2][4][4][512];   // 32 KB (hi/lo planes)
    __shared__ __bf16 Bim[2][4][4][512];   // 32 KB
    const int tid = threadIdx.x;
    const int lane = tid & 63, w = tid >> 6;
    const int g = lane >> 4, q = lane & 15;
    const int n0 = blockIdx.x * 64, m0 = blockIdx.y * 64;
    f32x4 acc[4] = {{0,0,0,0},{0,0,0,0},{0,0,0,0},{0,0,0,0}};

    for (int ch = 0; ch < 8; ++ch) {       // 8 chunks of K=128
        __syncthreads();                   // previous compute done
        for (int i = tid; i < 2048; i += 256) {   // stage A (both planes)
            int pl = i >> 10, rem = i & 1023;
            int r = rem >> 4, cc = rem & 15;
            const __bf16* s = (pl ? xlo : xhi) + (size_t)(m0 + r) * RNN + ch * 128 + cc * 8;
            bf16x8 v = *(const bf16x8*)s;
            *(bf16x8*)&Aim[pl][r >> 4][cc >> 2][(((cc & 3) << 4) + (r & 15)) << 3] = v;
        }
        for (int i = tid; i < 2048; i += 256) {   // stage B (both planes)
            int pl = i >> 10, rem = i & 1023;
            int r = rem >> 4, cc = rem & 15;
            const __bf16* s = Wt + ((size_t)(pl ? 4096 : 0) + n0 + r) * 2048 + ch * 128 + cc * 8;
            bf16x8 v = *(const bf16x8*)s;
            *(bf16x8*)&Bim[pl][r >> 4][cc >> 2][(((cc & 3) << 4) + (r & 15)) << 3] = v;
        }
        __syncthreads();
#pragma unroll
        for (int kc = 0; kc < 4; ++kc) {
            bf16x8 bhf = *(const bf16x8*)&Bim[0][w][kc][lane << 3];
            bf16x8 blf = *(const bf16x8*)&Bim[1][w][kc][lane << 3];
#pragma unroll
            for (int mt = 0; mt < 4; ++mt) {
                bf16x8 ahf = *(const bf16x8*)&Aim[0][mt][kc][lane << 3];
                bf16x8 alf = *(const bf16x8*)&Aim[1][mt][kc][lane << 3];
                acc[mt] = __builtin_amdgcn_mfma_f32_16x16x32_bf16(ahf, bhf, acc[mt], 0, 0, 0);
                acc[mt] = __builtin_amdgcn_mfma_f32_16x16x32_bf16(alf, bhf, acc[mt], 0, 0, 0);
                acc[mt] = __builtin_amdgcn_mfma_f32_16x16x32_bf16(ahf, blf, acc[mt], 0, 0, 0);
            }
        }
    }
    const int n = n0 + w * 16 + q;
    const float bv = bias[n];
#pragma unroll
    for (int mt = 0; mt < 4; ++mt)
#pragma unroll
        for (int r = 0; r < 4; ++r) {
            int m = m0 + mt * 16 + g * 4 + r;
            zx[(size_t)m * 4096 + n] = acc[mt][r] + bv;
        }
}

// ---------------------------------------------------------------------------
// Flat single-level fence-free barriers (round-11 proven form).
__device__ __forceinline__ void bar_all(unsigned* slots, int bk, int tid,
                                        unsigned gen, bool poll) {
    drain_vm();
    __syncthreads();
    if (tid == 0) ast(&slots[bk * AR_STRIDE], gen);
    if (poll && tid < GBLK) {
        while (ald(&slots[tid * AR_STRIDE]) < gen) __builtin_amdgcn_s_sleep(1);
    }
    __syncthreads();
}
__device__ __forceinline__ void bar_gate(unsigned* slots, int bk, bool arrive,
                                         int tid, unsigned gen) {
    drain_vm();
    __syncthreads();
    if (arrive && tid == 0) ast(&slots[bk * AR_STRIDE], gen);
    if (tid < BATCH) {
        while (ald(&slots[tid * AR_STRIDE]) < gen) __builtin_amdgcn_s_sleep(1);
    }
    __syncthreads();
}

// ---------------------------------------------------------------------------
// Persistent per-layer recurrence + helpers.
// Blocks 0..127: recurrence (coarse barriers, round-11 form).
// Blocks 128..255: mode 0 (l<3) -> zx(l+1) helpers; mode 1 (l=3) -> proj
// helpers streaming logit tiles as layer-3 h becomes available.
__global__ __launch_bounds__(256, 1) void k_rnn(
        const __bf16* __restrict__ Wl,    // layer base [2][4096][2048]
        float* __restrict__ zx,           // [SEQ*32][4096] (bias folded)
        float* __restrict__ z,            // [32][4096] scratch (sc1 only)
        __bf16* __restrict__ xhi, __bf16* __restrict__ xlo,  // [SEQ*32][1024]
        const float* __restrict__ g5, const float* __restrict__ b5,
        unsigned* bar, unsigned gen0,
        const __bf16* __restrict__ Wn,    // next-layer base (mode 0)
        const float* __restrict__ bias_n, // next-layer bias (mode 0)
        int mode,                         // 0 = zx helpers, 1 = proj helpers
        const __bf16* __restrict__ pw,    // smw bf16 [32000][1024] (mode 1)
        const float* __restrict__ psb,    // smb (mode 1)
        float* __restrict__ pout)         // logits (mode 1)
{
    __shared__ __bf16 wl[2][32768];       // 128 KB weight slice (lane-read order)
    __shared__ f32x4 pred[2][2][64];      // 4 KB partial accs [mt][nt][lane]
    __shared__ float red[4][8];
    unsigned* bar2 = bar + GBLK * AR_STRIDE;

    const int bk = blockIdx.x, tid = threadIdx.x;
    const int lane = tid & 63, w = tid >> 6;
    const int q = lane & 15, g = lane >> 4;
    const int mt = w & 1, kh = w >> 1;
    const int zr0  = (mt << 4) + (g << 2);

    // ======================= helper blocks (128..255) =======================
    if (bk >= GBLK) {
        if (mode == 1) {
            // ---- projection helpers: stream 128x128 logit tiles ----
            __bf16* As = &wl[0][0];       // [2][8][512] = 16384 elems (32 KB)
            __bf16* Bs = &wl[0][16384];
            const int wm = w & 1, wn = w >> 1;
            const int lr = lane >> 2, cc4 = lane & 3;
            const int gidx = cc4 * 16 + lr;
            for (int tau = bk - GBLK; tau < NTILES; tau += GBLK) {
                const int tt = tau / NTILES_N;
                const int n0p = (tau - tt * NTILES_N) * 128;
                const unsigned gneed = gen0 + 4u * (unsigned)tt + 4u;
                if (tid < BATCH) {
                    while (ald(&bar2[tid * AR_STRIDE]) < gneed)
                        __builtin_amdgcn_s_sleep(1);
                }
                __syncthreads();
                // tile GEMM: A = xhi rows [tt*128,+128), B = pw rows [n0p,+128)
                const __bf16* asrc[2];
                const __bf16* bsrc[2];
#pragma unroll
                for (int p2 = 0; p2 < 2; ++p2) {
                    int st = p2 * 4 + w;
                    asrc[p2] = xhi + (size_t)(tt * 128 + st * 16 + lr) * RNN + cc4 * 8;
                    bsrc[p2] = pw  + (size_t)(n0p + st * 16 + lr) * RNN + cc4 * 8;
                }
                f32x4 acc[4][4];
#pragma unroll
                for (int i = 0; i < 4; ++i)
#pragma unroll
                    for (int j = 0; j < 4; ++j) acc[i][j] = (f32x4){0.f,0.f,0.f,0.f};
                bf16x8 ar[2], br[2];
#pragma unroll
                for (int p2 = 0; p2 < 2; ++p2) {
                    ar[p2] = *(const bf16x8*)(asrc[p2]);
                    br[p2] = *(const bf16x8*)(bsrc[p2]);
                }
#pragma unroll
                for (int p2 = 0; p2 < 2; ++p2) {
                    int st = p2 * 4 + w;
                    *(bf16x8*)&As[st * 512 + gidx * 8] = ar[p2];
                    *(bf16x8*)&Bs[st * 512 + gidx * 8] = br[p2];
                }
                __syncthreads();
                for (int s = 0; s < 32; ++s) {
                    const int buf = s & 1;
                    if (s + 1 < 32) {
                        const int k0 = (s + 1) * 32;
#pragma unroll
                        for (int p2 = 0; p2 < 2; ++p2) {
                            ar[p2] = *(const bf16x8*)(asrc[p2] + k0);
                            br[p2] = *(const bf16x8*)(bsrc[p2] + k0);
                        }
                    }
                    bf16x8 af[4], bfr[4];
#pragma unroll
                    for (int i = 0; i < 4; ++i) {
                        af[i]  = *(const bf16x8*)&As[(buf * 8 + wm * 4 + i) * 512 + lane * 8];
                        bfr[i] = *(const bf16x8*)&Bs[(buf * 8 + wn * 4 + i) * 512 + lane * 8];
                    }
#pragma unroll
                    for (int mi = 0; mi < 4; ++mi)
#pragma unroll
                        for (int ni = 0; ni < 4; ++ni)
                            acc[mi][ni] = __builtin_amdgcn_mfma_f32_16x16x32_bf16(
                                af[mi], bfr[ni], acc[mi][ni], 0, 0, 0);
                    if (s + 1 < 32) {
#pragma unroll
                        for (int p2 = 0; p2 < 2; ++p2) {
                            int st = p2 * 4 + w;
                            *(bf16x8*)&As[((buf ^ 1) * 8 + st) * 512 + gidx * 8] = ar[p2];
                            *(bf16x8*)&Bs[((buf ^ 1) * 8 + st) * 512 + gidx * 8] = br[p2];
                        }
                    }
                    __syncthreads();
                }
#pragma unroll
                for (int ni = 0; ni < 4; ++ni) {
                    const int n = n0p + wn * 64 + ni * 16 + q;
                    const float bv = psb[n];
#pragma unroll
                    for (int mi = 0; mi < 4; ++mi) {
                        const int rb = wm * 64 + mi * 16 + g * 4;
#pragma unroll
                        for (int r = 0; r < 4; ++r) {
                            const int R = tt * 128 + rb + r;     // time-major row
                            const int m = (R & 31) * 128 + (R >> 5);  // out row
                            __builtin_nontemporal_store(acc[mi][ni][r] + bv,
                                                        &pout[(size_t)m * VOCAB + n]);
                        }
                    }
                }
            }
            return;
        }
        // ---- zx helpers (mode 0): compute zx(l+1)[t] after h(l)[t] ----
        const int hk = bk - GBLK;
        const int ncolh = (hk << 5) + q;
        {
            const __bf16* hi_src = Wn + ((size_t)(hk << 5)) * 2048;
            const __bf16* lo_src = Wn + ((size_t)(4096 + (hk << 5))) * 2048;
            for (int i = tid; i < 8192; i += 256) {
                int pl = i >> 12, rem = i & 4095;
                int r = rem >> 7, cc = rem & 127;
                const __bf16* s = (pl ? lo_src : hi_src) + (size_t)r * 2048 + cc * 8;
                bf16x8 v = *(const bf16x8*)s;
                int rnt = r >> 4, rq = r & 15, kc = cc >> 2, rg = cc & 3;
                *(bf16x8*)&wl[pl][((rnt * 32 + kc) << 9) + ((rg * 16 + rq) << 3)] = v;
            }
        }
        float bv0 = 0.f, bv1 = 0.f;
        if (kh == 0) { bv0 = bias_n[ncolh]; bv1 = bias_n[ncolh + 16]; }
        __syncthreads();
        const __bf16* hb0 = &wl[0][0]        + (lane << 3);
        const __bf16* lb0 = &wl[1][0]        + (lane << 3);
        const __bf16* hb1 = &wl[0][32 << 9]  + (lane << 3);
        const __bf16* lb1 = &wl[1][32 << 9]  + (lane << 3);

        for (int t = 0; t < SEQ; ++t) {
            const unsigned gen = gen0 + (unsigned)t + 1u;
            if (tid < BATCH) {     // wait for h(l)[t]
                while (ald(&bar2[tid * AR_STRIDE]) < gen) __builtin_amdgcn_s_sleep(1);
            }
            __syncthreads();
            const __bf16* ah = xhi + ((size_t)t * BATCH + (mt << 4) + q) * RNN;
            const __bf16* al = xlo + ((size_t)t * BATCH + (mt << 4) + q) * RNN;
            f32x4 a00={0,0,0,0}, a01={0,0,0,0}, a02={0,0,0,0};
            f32x4 a10={0,0,0,0}, a11={0,0,0,0}, a12={0,0,0,0};
            const int k0 = kh << 4;
#pragma unroll 4
            for (int kc = k0; kc < k0 + 16; ++kc) {
                bf16x8 ahf = *(const bf16x8*)(ah + (kc << 5) + (g << 3));
                bf16x8 alf = *(const bf16x8*)(al + (kc << 5) + (g << 3));
                bf16x8 b0h = *(const bf16x8*)(hb0 + (kc << 9));
                bf16x8 b0l = *(const bf16x8*)(lb0 + (kc << 9));
                bf16x8 b1h = *(const bf16x8*)(hb1 + (kc << 9));
                bf16x8 b1l = *(const bf16x8*)(lb1 + (kc << 9));
                a00 = __builtin_amdgcn_mfma_f32_16x16x32_bf16(ahf, b0h, a00, 0, 0, 0);
                a01 = __builtin_amdgcn_mfma_f32_16x16x32_bf16(alf, b0h, a01, 0, 0, 0);
                a02 = __builtin_amdgcn_mfma_f32_16x16x32_bf16(ahf, b0l, a02, 0, 0, 0);
                a10 = __builtin_amdgcn_mfma_f32_16x16x32_bf16(ahf, b1h, a10, 0, 0, 0);
                a11 = __builtin_amdgcn_mfma_f32_16x16x32_bf16(alf, b1h, a11, 0, 0, 0);
                a12 = __builtin_amdgcn_mfma_f32_16x16x32_bf16(ahf, b1l, a12, 0, 0, 0);
            }
            f32x4 s0, s1;
#pragma unroll
            for (int j = 0; j < 4; ++j) {
                s0[j] = a00[j] + a01[j] + a02[j];
                s1[j] = a10[j] + a11[j] + a12[j];
            }
            if (kh == 1) { pred[mt][0][lane] = s0; pred[mt][1][lane] = s1; }
            __syncthreads();
            if (kh == 0) {
                f32x4 p0 = pred[mt][0][lane], p1 = pred[mt][1][lane];
#pragma unroll
                for (int r = 0; r < 4; ++r) {
                    zx[((size_t)t * BATCH + zr0 + r) * 4096 + ncolh]      = s0[r] + p0[r] + bv0;
                    zx[((size_t)t * BATCH + zr0 + r) * 4096 + ncolh + 16] = s1[r] + p1[r] + bv1;
                }
            }
            __syncthreads();   // pred WAR across t
        }
        return;
    }

    // ======================= recurrence blocks (0..127) =====================
    const int ncol = (bk << 5) + q;       // nt=0 col; nt=1 at +16

    // ---- stage Wh hi+lo into LDS (lane-read order) ----
    {
        const __bf16* hi_src = Wl + ((size_t)(bk << 5)) * 2048 + RNN;
        const __bf16* lo_src = Wl + ((size_t)(4096 + (bk << 5))) * 2048 + RNN;
        for (int i = tid; i < 8192; i += 256) {
            int pl = i >> 12, rem = i & 4095;
            int r = rem >> 7, cc = rem & 127;
            const __bf16* s = (pl ? lo_src : hi_src) + (size_t)r * 2048 + cc * 8;
            bf16x8 v = *(const bf16x8*)s;
            int rnt = r >> 4, rq = r & 15, kc = cc >> 2, rg = cc & 3;
            *(bf16x8*)&wl[pl][((rnt * 32 + kc) << 9) + ((rg * 16 + rq) << 3)] = v;
        }
    }

    // ---- gate-block constants (blocks 0..31) ----
    const bool is_gate = (bk < BATCH);
    f32x4 gi, bi, gj, bj, gf, bfv, go, bo, g4, b4;
    if (is_gate) {
        gi = *(const f32x4*)(g5 + 0*RNN + tid*4); bi = *(const f32x4*)(b5 + 0*RNN + tid*4);
        gj = *(const f32x4*)(g5 + 1*RNN + tid*4); bj = *(const f32x4*)(b5 + 1*RNN + tid*4);
        gf = *(const f32x4*)(g5 + 2*RNN + tid*4); bfv= *(const f32x4*)(b5 + 2*RNN + tid*4);
        go = *(const f32x4*)(g5 + 3*RNN + tid*4); bo = *(const f32x4*)(b5 + 3*RNN + tid*4);
        g4 = *(const f32x4*)(g5 + 4*RNN + tid*4); b4 = *(const f32x4*)(b5 + 4*RNN + tid*4);
    }
    const float inv = 1.f / (float)RNN;
    f32x4 creg = {0.f, 0.f, 0.f, 0.f};    // cell state lives in registers
    __syncthreads();   // LDS staged

    const __bf16* bh0 = &wl[0][0]        + (lane << 3);   // nt=0 hi (+kc<<9)
    const __bf16* bl0 = &wl[1][0]        + (lane << 3);   // nt=0 lo
    const __bf16* bh1 = &wl[0][32 << 9]  + (lane << 3);   // nt=1 hi
    const __bf16* bl1 = &wl[1][32 << 9]  + (lane << 3);   // nt=1 lo

    // zx prefetch (t = 0), kh0 waves only (they finalize z)
    float zv0[4], zv1[4];
    if (kh == 0) {
        const float* zxp = zx + (size_t)zr0 * 4096 + ncol;
#pragma unroll
        for (int r = 0; r < 4; ++r) {
            zv0[r] = zxp[(size_t)r * 4096];
            zv1[r] = zxp[(size_t)r * 4096 + 16];
        }
    }

    for (int t = 0; t < SEQ; ++t) {
        const unsigned gen = gen0 + (unsigned)t + 1u;
        // ---- phase A: z_t = zx[t] + h_{t-1} @ Wh (K-split across waves) ----
        f32x4 a00={0,0,0,0}, a01={0,0,0,0}, a02={0,0,0,0};
        f32x4 a10={0,0,0,0}, a11={0,0,0,0}, a12={0,0,0,0};
        if (t > 0) {
            const __bf16* ah = xhi + ((size_t)(t - 1) * BATCH + (mt << 4) + q) * RNN;
            const __bf16* al = xlo + ((size_t)(t - 1) * BATCH + (mt << 4) + q) * RNN;
            const int k0 = kh << 4;
#pragma unroll 4
            for (int kc = k0; kc < k0 + 16; ++kc) {
                bf16x8 ahf = *(const bf16x8*)(ah + (kc << 5) + (g << 3));   // normal 16B
                bf16x8 alf = *(const bf16x8*)(al + (kc << 5) + (g << 3));
                bf16x8 b0h = *(const bf16x8*)(bh0 + (kc << 9));
                bf16x8 b0l = *(const bf16x8*)(bl0 + (kc << 9));
                bf16x8 b1h = *(const bf16x8*)(bh1 + (kc << 9));
                bf16x8 b1l = *(const bf16x8*)(bl1 + (kc << 9));
                a00 = __builtin_amdgcn_mfma_f32_16x16x32_bf16(ahf, b0h, a00, 0, 0, 0);
                a01 = __builtin_amdgcn_mfma_f32_16x16x32_bf16(alf, b0h, a01, 0, 0, 0);
                a02 = __builtin_amdgcn_mfma_f32_16x16x32_bf16(ahf, b0l, a02, 0, 0, 0);
                a10 = __builtin_amdgcn_mfma_f32_16x16x32_bf16(ahf, b1h, a10, 0, 0, 0);
                a11 = __builtin_amdgcn_mfma_f32_16x16x32_bf16(alf, b1h, a11, 0, 0, 0);
                a12 = __builtin_amdgcn_mfma_f32_16x16x32_bf16(ahf, b1l, a12, 0, 0, 0);
            }
        }
        {
            f32x4 s0, s1;
#pragma unroll
            for (int j = 0; j < 4; ++j) {
                s0[j] = a00[j] + a01[j] + a02[j];
                s1[j] = a10[j] + a11[j] + a12[j];
            }
            if (kh == 1) { pred[mt][0][lane] = s0; pred[mt][1][lane] = s1; }
            __syncthreads();
            if (kh == 0) {
                f32x4 p0 = pred[mt][0][lane], p1 = pred[mt][1][lane];
#pragma unroll
                for (int r = 0; r < 4; ++r) {
                    astf(&z[(size_t)(zr0 + r) * 4096 + ncol],      s0[r] + p0[r] + zv0[r]);
                    astf(&z[(size_t)(zr0 + r) * 4096 + ncol + 16], s1[r] + p1[r] + zv1[r]);
                }
            }
        }
        bar_all(bar, bk, tid, gen, is_gate);   // z visible (only gates wait)

        // ---- prefetch zx for t+1 (hides under phase B) ----
        if (kh == 0 && t + 1 < SEQ) {
            const float* zxp = zx + ((size_t)(t + 1) * BATCH + zr0) * 4096 + ncol;
#pragma unroll
            for (int r = 0; r < 4; ++r) {
                zv0[r] = zxp[(size_t)r * 4096];
                zv1[r] = zxp[(size_t)r * 4096 + 16];
            }
        }

        // ---- phase B: gates (blocks 0..31), c in registers ----
        if (is_gate) {
            const int b = bk;
            const float* zrow = z + (size_t)b * 4096 + tid * 4;
            auto ld4 = [&](const float* p) -> f32x4 {
                U128F x;
                x.u[0] = ald64((const unsigned long long*)p);
                x.u[1] = ald64((const unsigned long long*)p + 1);
                return x.f;
            };
            f32x4 zi = ld4(zrow), zjv = ld4(zrow + 1024),
                  zfv = ld4(zrow + 2048), zov = ld4(zrow + 3072);
            float s[8];
            s[0] = zi[0]+zi[1]+zi[2]+zi[3];
            s[1] = zi[0]*zi[0]+zi[1]*zi[1]+zi[2]*zi[2]+zi[3]*zi[3];
            s[2] = zjv[0]+zjv[1]+zjv[2]+zjv[3];
            s[3] = zjv[0]*zjv[0]+zjv[1]*zjv[1]+zjv[2]*zjv[2]+zjv[3]*zjv[3];
            s[4] = zfv[0]+zfv[1]+zfv[2]+zfv[3];
            s[5] = zfv[0]*zfv[0]+zfv[1]*zfv[1]+zfv[2]*zfv[2]+zfv[3]*zfv[3];
            s[6] = zov[0]+zov[1]+zov[2]+zov[3];
            s[7] = zov[0]*zov[0]+zov[1]*zov[1]+zov[2]*zov[2]+zov[3]*zov[3];
#pragma unroll
            for (int o = 32; o; o >>= 1)
#pragma unroll
                for (int i = 0; i < 8; ++i) s[i] += __shfl_xor(s[i], o);
            if (lane == 0) {
#pragma unroll
                for (int i = 0; i < 8; ++i) red[w][i] = s[i];
            }
            __syncthreads();
            float tot[8];
#pragma unroll
            for (int i = 0; i < 8; ++i) tot[i] = red[0][i]+red[1][i]+red[2][i]+red[3][i];

            float mi = tot[0]*inv, ri = rsqrtf(tot[1]*inv - mi*mi + 1e-5f);
            float mj = tot[2]*inv, rj = rsqrtf(tot[3]*inv - mj*mj + 1e-5f);
            float mf = tot[4]*inv, rf = rsqrtf(tot[5]*inv - mf*mf + 1e-5f);
            float mo = tot[6]*inv, ro = rsqrtf(tot[7]*inv - mo*mo + 1e-5f);

            f32x4 onrm;
            float cs = 0.f, cq = 0.f;
#pragma unroll
            for (int j = 0; j < 4; ++j) {
                float iv = (zi[j]-mi)*ri*gi[j] + bi[j];
                float jv = (zjv[j]-mj)*rj*gj[j] + bj[j];
                float fv = (zfv[j]-mf)*rf*gf[j] + bfv[j];
                float ov = (zov[j]-mo)*ro*go[j] + bo[j];
                float cc = creg[j] * sigm(fv + 1.0f) + sigm(iv) * tanhf(jv);
                creg[j] = cc; onrm[j] = ov;
                cs += cc; cq += cc*cc;
            }

            __syncthreads();   // protect red[] reuse
            float s2a = cs, s2b = cq;
#pragma unroll
            for (int o = 32; o; o >>= 1) { s2a += __shfl_xor(s2a, o); s2b += __shfl_xor(s2b, o); }
            if (lane == 0) { red[w][0] = s2a; red[w][1] = s2b; }
            __syncthreads();
            float mc = (red[0][0]+red[1][0]+red[2][0]+red[3][0]) * inv;
            float vc = (red[0][1]+red[1][1]+red[2][1]+red[3][1]) * inv - mc*mc;
            float rc = rsqrtf(vc + 1e-5f);

            bf16x4 hh, hl;
#pragma unroll
            for (int j = 0; j < 4; ++j) {
                float cn = (creg[j]-mc)*rc*g4[j] + b4[j];
                float h = tanhf(cn) * sigm(onrm[j]);
                __bf16 a = (__bf16)h;
                hh[j] = a; hl[j] = (__bf16)(h - (float)a);
            }
            U64B ph, pl;
            ph.v = hh; pl.v = hl;
            // single h store: time-indexed x buffers (sc1 -> coherence point)
            ast64((unsigned long long*)&xhi[((size_t)t * BATCH + b) * RNN + tid * 4], ph.u);
            ast64((unsigned long long*)&xlo[((size_t)t * BATCH + b) * RNN + tid * 4], pl.u);
        }
        bar_gate(bar2, bk, is_gate, tid, gen);   // h visible
    }
}

// ---------------------------------------------------------------------------
extern "C" void kernel_launch(void* const* d_in, const int* in_sizes, int n_in,
                              void* d_out, int out_size, void* d_ws, size_t ws_size,
                              hipStream_t stream) {
    const int*   input = (const int*)  d_in[0];
    const float* emb   = (const float*)d_in[1];
    const float* W     = (const float*)d_in[2];
    const float* bias  = (const float*)d_in[3];
    const float* ln_g  = (const float*)d_in[4];
    const float* ln_b  = (const float*)d_in[5];
    const float* smw   = (const float*)d_in[6];
    const float* smb   = (const float*)d_in[7];
    float* out = (float*)d_out;

    char* p = (char*)d_ws;
    auto alloc = [&](size_t bytes) { char* r = p; p += (bytes + 255) & ~(size_t)255; return r; };
    __bf16* Wt   = (__bf16*)alloc((size_t)NLAY * 2 * 4096 * 2048 * 2); // 134.2 MB
    __bf16* smwb = (__bf16*)alloc((size_t)VOCAB * RNN * 2);            // 65.5 MB
    __bf16* xhi  = (__bf16*)alloc((size_t)SEQ * BATCH * RNN * 2);      // 8.4 MB
    __bf16* xlo  = (__bf16*)alloc((size_t)SEQ * BATCH * RNN * 2);      // 8.4 MB
    float*  zx   = (float*) alloc((size_t)SEQ * BATCH * 4096 * 4);     // 67.1 MB
    float*  z    = (float*) alloc((size_t)BATCH * 4096 * 4);           // 512 KB
    unsigned* bar= (unsigned*)alloc(2 * GBLK * AR_STRIDE * 4);         // 2 slot arrays

    hipMemsetAsync(bar, 0, 2 * GBLK * AR_STRIDE * 4, stream);

    k_cvt_w<<<dim3(64, 32, NLAY), 256, 0, stream>>>(W, Wt);
    k_cvt<<<(VOCAB * RNN) / (8 * 256), 256, 0, stream>>>(smw, smwb);
    k_embed<<<SEQ * BATCH, 256, 0, stream>>>(input, emb, xhi, xlo);

    // zx for layer 0 (all x available upfront)
    k_xgemm<<<dim3(64, 64), 256, 0, stream>>>(xhi, xlo, Wt, bias, zx);

    for (int l = 0; l < NLAY; ++l) {
        const __bf16* Wl  = Wt + (size_t)l * 2 * 4096 * 2048;
        const float*  gl  = ln_g + (size_t)l * 5 * RNN;
        const float*  bbl = ln_b + (size_t)l * 5 * RNN;
        const int lnext = (l + 1 < NLAY) ? (l + 1) : l;   // dummy for l=3
        const __bf16* Wn  = Wt + (size_t)lnext * 2 * 4096 * 2048;
        const float*  bn  = bias + (size_t)lnext * 4096;
        {
            const __bf16* Wl_ = Wl;
            float* zx_ = zx;
            float* z_ = z;
            __bf16 *xhi_ = xhi, *xlo_ = xlo;
            const float *gl_ = gl, *bbl_ = bbl;
            unsigned* bar_ = bar;
            unsigned gen0 = (unsigned)(l * SEQ);
            const __bf16* Wn_ = Wn;
            const float* bn_ = bn;
            int mode = (l + 1 < NLAY) ? 0 : 1;
            const __bf16* pw_ = smwb;
            const float* psb_ = smb;
            float* pout_ = out;
            void* args[] = {(void*)&Wl_, (void*)&zx_, (void*)&z_,
                            (void*)&xhi_, (void*)&xlo_, (void*)&gl_, (void*)&bbl_,
                            (void*)&bar_, (void*)&gen0, (void*)&Wn_, (void*)&bn_,
                            (void*)&mode, (void*)&pw_, (void*)&psb_, (void*)&pout_};
            // 256 blocks always: 128 recurrence + 128 helpers
            // (l<3: zx helpers; l=3: projection helpers)
            hipLaunchCooperativeKernel((const void*)k_rnn,
                                       dim3(2 * GBLK), dim3(256), args, 0, stream);
        }
    }
    // projection is produced inside the l=3 launch (proj helpers)
}

// Round 15
// 5372.404 us; speedup vs baseline: 1.1727x; 1.0696x over previous
//
#include <hip/hip_runtime.h>
#include <hip/hip_bf16.h>

// CharRNN: embed -> 4x (LayerNorm-LSTM over T=128) -> projection to vocab.
// Round 14: fold layer-0's x-GEMM into the l=0 launch. Helpers (blocks
// 128-255) run a pre-phase: stage Wx(0), compute zx(0)[t] at full speed
// (sc1 stores; per-block ready-slot bar3, 1:1 with the consuming col-block),
// then restage Wx(1) and run the normal zx(1) tracking loop. Col-blocks
// poll their single bar3 slot before each zx prefetch (l=0 only).
// k_xgemm dispatch eliminated (~340us serial). l=3 proj-fold unchanged.

typedef __bf16 bf16x8 __attribute__((ext_vector_type(8)));
typedef __bf16 bf16x4 __attribute__((ext_vector_type(4)));
typedef float  f32x4  __attribute__((ext_vector_type(4)));

#define VOCAB 32000
#define BATCH 32
#define SEQ   128
#define RNN   1024
#define NLAY  4
#define GBLK  128
#define AR_STRIDE 16            // dwords between arrival slots (64 B)
#define NTILES_N 250            // 32000 / 128
#define NTILES_T 32             // 4096 / 128
#define NTILES  (NTILES_N * NTILES_T)

__device__ __forceinline__ float sigm(float x) { return 1.f / (1.f + __expf(-x)); }

// ---- agent-scope relaxed atomics (sc1: coherence-point, bypass stale L2) ----
__device__ __forceinline__ unsigned ald(const unsigned* p) {
    return __hip_atomic_load(p, __ATOMIC_RELAXED, __HIP_MEMORY_SCOPE_AGENT);
}
__device__ __forceinline__ void ast(unsigned* p, unsigned v) {
    __hip_atomic_store(p, v, __ATOMIC_RELAXED, __HIP_MEMORY_SCOPE_AGENT);
}
__device__ __forceinline__ unsigned long long ald64(const unsigned long long* p) {
    return __hip_atomic_load(p, __ATOMIC_RELAXED, __HIP_MEMORY_SCOPE_AGENT);
}
__device__ __forceinline__ void ast64(unsigned long long* p, unsigned long long v) {
    __hip_atomic_store(p, v, __ATOMIC_RELAXED, __HIP_MEMORY_SCOPE_AGENT);
}
__device__ __forceinline__ void astf(float* p, float v) {
    __hip_atomic_store(p, v, __ATOMIC_RELAXED, __HIP_MEMORY_SCOPE_AGENT);
}
__device__ __forceinline__ void drain_vm() {
    asm volatile("s_waitcnt vmcnt(0)" ::: "memory");
}

typedef union { unsigned long long u[2]; f32x4 f; }  U128F;
typedef union { unsigned long long u; bf16x4 v; }    U64B;

// ---------------------------------------------------------------------------
// W [L][2048][4096] f32 -> Wt [L][2 planes (hi,lo)][4096][2048] bf16,
// transposed to [n][k]. k 0..1023 = x-part (Wx), k 1024..2047 = h-part (Wh).
__global__ __launch_bounds__(256) void k_cvt_w(const float* __restrict__ W,
                                               __bf16* __restrict__ Wt) {
    __shared__ float lds[64][65];
    const int tid = threadIdx.x, tx = tid & 15, ty = tid >> 4;
    const int n0 = blockIdx.x * 64, k0 = blockIdx.y * 64;
    const size_t l = blockIdx.z;
    const float* src = W + (l * 2048 + (size_t)k0) * 4096 + n0;
#pragma unroll
    for (int rr = 0; rr < 4; ++rr) {
        int kr = rr * 16 + ty;
        f32x4 v = *(const f32x4*)(src + (size_t)kr * 4096 + tx * 4);
        lds[kr][tx*4+0] = v[0]; lds[kr][tx*4+1] = v[1];
        lds[kr][tx*4+2] = v[2]; lds[kr][tx*4+3] = v[3];
    }
    __syncthreads();
    __bf16* dhi = Wt + ((l * 2 + 0) * 4096 + (size_t)n0) * 2048 + k0;
    __bf16* dlo = Wt + ((l * 2 + 1) * 4096 + (size_t)n0) * 2048 + k0;
#pragma unroll
    for (int rr = 0; rr < 4; ++rr) {
        int nr = rr * 16 + ty;
        bf16x4 ohi, olo;
#pragma unroll
        for (int j = 0; j < 4; ++j) {
            float x = lds[tx*4+j][nr];
            __bf16 h = (__bf16)x;
            ohi[j] = h;
            olo[j] = (__bf16)(x - (float)h);
        }
        *(bf16x4*)(dhi + (size_t)nr * 2048 + tx * 4) = ohi;
        *(bf16x4*)(dlo + (size_t)nr * 2048 + tx * 4) = olo;
    }
}

// plain f32 -> bf16 (hi only), 8 elems/thread, exact grid
__global__ __launch_bounds__(256) void k_cvt(const float* __restrict__ in,
                                             __bf16* __restrict__ out) {
    size_t i = ((size_t)blockIdx.x * 256 + threadIdx.x) * 8;
    f32x4 v0 = *(const f32x4*)(in + i);
    f32x4 v1 = *(const f32x4*)(in + i + 4);
    bf16x8 o;
    o[0]=(__bf16)v0[0]; o[1]=(__bf16)v0[1]; o[2]=(__bf16)v0[2]; o[3]=(__bf16)v0[3];
    o[4]=(__bf16)v1[0]; o[5]=(__bf16)v1[1]; o[6]=(__bf16)v1[2]; o[7]=(__bf16)v1[3];
    *(bf16x8*)(out + i) = o;
}

// embedding gather -> time-major [t*32+b][1024] hi/lo bf16
__global__ __launch_bounds__(256) void k_embed(const int* __restrict__ idx,
                                               const float* __restrict__ emb,
                                               __bf16* __restrict__ xhi,
                                               __bf16* __restrict__ xlo) {
    const int row = blockIdx.x;            // t*32 + b
    const int t = row >> 5, b = row & 31;
    const int id = idx[b * SEQ + t];
    const int tid = threadIdx.x;
    f32x4 v = *(const f32x4*)(emb + (size_t)id * RNN + tid * 4);
    bf16x4 hi, lo;
#pragma unroll
    for (int j = 0; j < 4; ++j) {
        __bf16 h = (__bf16)v[j];
        hi[j] = h; lo[j] = (__bf16)(v[j] - (float)h);
    }
    *(bf16x4*)(xhi + (size_t)row * RNN + tid * 4) = hi;
    *(bf16x4*)(xlo + (size_t)row * RNN + tid * 4) = lo;
}

// ---------------------------------------------------------------------------
// Flat single-level fence-free barriers (round-11 proven form).
__device__ __forceinline__ void bar_all(unsigned* slots, int bk, int tid,
                                        unsigned gen, bool poll) {
    drain_vm();
    __syncthreads();
    if (tid == 0) ast(&slots[bk * AR_STRIDE], gen);
    if (poll && tid < GBLK) {
        while (ald(&slots[tid * AR_STRIDE]) < gen) __builtin_amdgcn_s_sleep(1);
    }
    __syncthreads();
}
__device__ __forceinline__ void bar_gate(unsigned* slots, int bk, bool arrive,
                                         int tid, unsigned gen) {
    drain_vm();
    __syncthreads();
    if (arrive && tid == 0) ast(&slots[bk * AR_STRIDE], gen);
    if (tid < BATCH) {
        while (ald(&slots[tid * AR_STRIDE]) < gen) __builtin_amdgcn_s_sleep(1);
    }
    __syncthreads();
}

// ---------------------------------------------------------------------------
// Persistent per-layer recurrence + helpers.
// Blocks 0..127: recurrence (coarse barriers).
// Blocks 128..255: mode 0 (l=1,2) -> zx(l+1) helpers; mode 1 (l=3) -> proj
// helpers; mode 2 (l=0) -> zx(0) pre-phase (sc1 stores + bar3 slots) then
// zx(1) tracking loop.
__global__ __launch_bounds__(256, 1) void k_rnn(
        const __bf16* __restrict__ Wl,    // layer base [2][4096][2048]
        float* __restrict__ zx,           // [SEQ*32][4096] (bias folded)
        float* __restrict__ z,            // [32][4096] scratch (sc1 only)
        __bf16* __restrict__ xhi, __bf16* __restrict__ xlo,  // [SEQ*32][1024]
        const float* __restrict__ g5, const float* __restrict__ b5,
        unsigned* bar, unsigned gen0,
        const __bf16* __restrict__ Wn,    // next-layer base (mode 0/2)
        const float* __restrict__ bias_n, // next-layer bias (mode 0/2)
        const float* __restrict__ bias_l, // this-layer bias (mode 2)
        int mode,
        const __bf16* __restrict__ pw,    // smw bf16 (mode 1)
        const float* __restrict__ psb,    // smb (mode 1)
        float* __restrict__ pout)         // logits (mode 1)
{
    __shared__ __bf16 wl[2][32768];       // 128 KB weight slice (lane-read order)
    __shared__ f32x4 pred[2][2][64];      // 4 KB partial accs [mt][nt][lane]
    __shared__ float red[4][8];
    unsigned* bar2 = bar + GBLK * AR_STRIDE;
    unsigned* bar3 = bar + 2 * GBLK * AR_STRIDE;

    const int bk = blockIdx.x, tid = threadIdx.x;
    const int lane = tid & 63, w = tid >> 6;
    const int q = lane & 15, g = lane >> 4;
    const int mt = w & 1, kh = w >> 1;
    const int zr0  = (mt << 4) + (g << 2);

    // ======================= helper blocks (128..255) =======================
    if (bk >= GBLK) {
        if (mode == 1) {
            // ---- projection helpers: stream 128x128 logit tiles ----
            __bf16* As = &wl[0][0];
            __bf16* Bs = &wl[0][16384];
            const int wm = w & 1, wn = w >> 1;
            const int lr = lane >> 2, cc4 = lane & 3;
            const int gidx = cc4 * 16 + lr;
            for (int tau = bk - GBLK; tau < NTILES; tau += GBLK) {
                const int tt = tau / NTILES_N;
                const int n0p = (tau - tt * NTILES_N) * 128;
                const unsigned gneed = gen0 + 4u * (unsigned)tt + 4u;
                if (tid < BATCH) {
                    while (ald(&bar2[tid * AR_STRIDE]) < gneed)
                        __builtin_amdgcn_s_sleep(1);
                }
                __syncthreads();
                const __bf16* asrc[2];
                const __bf16* bsrc[2];
#pragma unroll
                for (int p2 = 0; p2 < 2; ++p2) {
                    int st = p2 * 4 + w;
                    asrc[p2] = xhi + (size_t)(tt * 128 + st * 16 + lr) * RNN + cc4 * 8;
                    bsrc[p2] = pw  + (size_t)(n0p + st * 16 + lr) * RNN + cc4 * 8;
                }
                f32x4 acc[4][4];
#pragma unroll
                for (int i = 0; i < 4; ++i)
#pragma unroll
                    for (int j = 0; j < 4; ++j) acc[i][j] = (f32x4){0.f,0.f,0.f,0.f};
                bf16x8 ar[2], br[2];
#pragma unroll
                for (int p2 = 0; p2 < 2; ++p2) {
                    ar[p2] = *(const bf16x8*)(asrc[p2]);
                    br[p2] = *(const bf16x8*)(bsrc[p2]);
                }
#pragma unroll
                for (int p2 = 0; p2 < 2; ++p2) {
                    int st = p2 * 4 + w;
                    *(bf16x8*)&As[st * 512 + gidx * 8] = ar[p2];
                    *(bf16x8*)&Bs[st * 512 + gidx * 8] = br[p2];
                }
                __syncthreads();
                for (int s = 0; s < 32; ++s) {
                    const int buf = s & 1;
                    if (s + 1 < 32) {
                        const int k0 = (s + 1) * 32;
#pragma unroll
                        for (int p2 = 0; p2 < 2; ++p2) {
                            ar[p2] = *(const bf16x8*)(asrc[p2] + k0);
                            br[p2] = *(const bf16x8*)(bsrc[p2] + k0);
                        }
                    }
                    bf16x8 af[4], bfr[4];
#pragma unroll
                    for (int i = 0; i < 4; ++i) {
                        af[i]  = *(const bf16x8*)&As[(buf * 8 + wm * 4 + i) * 512 + lane * 8];
                        bfr[i] = *(const bf16x8*)&Bs[(buf * 8 + wn * 4 + i) * 512 + lane * 8];
                    }
#pragma unroll
                    for (int mi = 0; mi < 4; ++mi)
#pragma unroll
                        for (int ni = 0; ni < 4; ++ni)
                            acc[mi][ni] = __builtin_amdgcn_mfma_f32_16x16x32_bf16(
                                af[mi], bfr[ni], acc[mi][ni], 0, 0, 0);
                    if (s + 1 < 32) {
#pragma unroll
                        for (int p2 = 0; p2 < 2; ++p2) {
                            int st = p2 * 4 + w;
                            *(bf16x8*)&As[((buf ^ 1) * 8 + st) * 512 + gidx * 8] = ar[p2];
                            *(bf16x8*)&Bs[((buf ^ 1) * 8 + st) * 512 + gidx * 8] = br[p2];
                        }
                    }
                    __syncthreads();
                }
#pragma unroll
                for (int ni = 0; ni < 4; ++ni) {
                    const int n = n0p + wn * 64 + ni * 16 + q;
                    const float bv = psb[n];
#pragma unroll
                    for (int mi = 0; mi < 4; ++mi) {
                        const int rb = wm * 64 + mi * 16 + g * 4;
#pragma unroll
                        for (int r = 0; r < 4; ++r) {
                            const int R = tt * 128 + rb + r;
                            const int m = (R & 31) * 128 + (R >> 5);
                            __builtin_nontemporal_store(acc[mi][ni][r] + bv,
                                                        &pout[(size_t)m * VOCAB + n]);
                        }
                    }
                }
            }
            return;
        }
        const int hk = bk - GBLK;
        const int ncolh = (hk << 5) + q;

        if (mode == 2) {
            // ---- pre-phase: zx(0) from embedding x, no dependencies ----
            {
                const __bf16* hi_src = Wl + ((size_t)(hk << 5)) * 2048;
                const __bf16* lo_src = Wl + ((size_t)(4096 + (hk << 5))) * 2048;
                for (int i = tid; i < 8192; i += 256) {
                    int pl = i >> 12, rem = i & 4095;
                    int r = rem >> 7, cc = rem & 127;
                    const __bf16* s = (pl ? lo_src : hi_src) + (size_t)r * 2048 + cc * 8;
                    bf16x8 v = *(const bf16x8*)s;
                    int rnt = r >> 4, rq = r & 15, kc = cc >> 2, rg = cc & 3;
                    *(bf16x8*)&wl[pl][((rnt * 32 + kc) << 9) + ((rg * 16 + rq) << 3)] = v;
                }
            }
            float bv0 = 0.f, bv1 = 0.f;
            if (kh == 0) { bv0 = bias_l[ncolh]; bv1 = bias_l[ncolh + 16]; }
            __syncthreads();
            const __bf16* hb0 = &wl[0][0]        + (lane << 3);
            const __bf16* lb0 = &wl[1][0]        + (lane << 3);
            const __bf16* hb1 = &wl[0][32 << 9]  + (lane << 3);
            const __bf16* lb1 = &wl[1][32 << 9]  + (lane << 3);
            for (int t = 0; t < SEQ; ++t) {
                const __bf16* ah = xhi + ((size_t)t * BATCH + (mt << 4) + q) * RNN;
                const __bf16* al = xlo + ((size_t)t * BATCH + (mt << 4) + q) * RNN;
                f32x4 a00={0,0,0,0}, a01={0,0,0,0}, a02={0,0,0,0};
                f32x4 a10={0,0,0,0}, a11={0,0,0,0}, a12={0,0,0,0};
                const int k0 = kh << 4;
#pragma unroll 4
                for (int kc = k0; kc < k0 + 16; ++kc) {
                    bf16x8 ahf = *(const bf16x8*)(ah + (kc << 5) + (g << 3));
                    bf16x8 alf = *(const bf16x8*)(al + (kc << 5) + (g << 3));
                    bf16x8 b0h = *(const bf16x8*)(hb0 + (kc << 9));
                    bf16x8 b0l = *(const bf16x8*)(lb0 + (kc << 9));
                    bf16x8 b1h = *(const bf16x8*)(hb1 + (kc << 9));
                    bf16x8 b1l = *(const bf16x8*)(lb1 + (kc << 9));
                    a00 = __builtin_amdgcn_mfma_f32_16x16x32_bf16(ahf, b0h, a00, 0, 0, 0);
                    a01 = __builtin_amdgcn_mfma_f32_16x16x32_bf16(alf, b0h, a01, 0, 0, 0);
                    a02 = __builtin_amdgcn_mfma_f32_16x16x32_bf16(ahf, b0l, a02, 0, 0, 0);
                    a10 = __builtin_amdgcn_mfma_f32_16x16x32_bf16(ahf, b1h, a10, 0, 0, 0);
                    a11 = __builtin_amdgcn_mfma_f32_16x16x32_bf16(alf, b1h, a11, 0, 0, 0);
                    a12 = __builtin_amdgcn_mfma_f32_16x16x32_bf16(ahf, b1l, a12, 0, 0, 0);
                }
                f32x4 s0, s1;
#pragma unroll
                for (int j = 0; j < 4; ++j) {
                    s0[j] = a00[j] + a01[j] + a02[j];
                    s1[j] = a10[j] + a11[j] + a12[j];
                }
                if (kh == 1) { pred[mt][0][lane] = s0; pred[mt][1][lane] = s1; }
                __syncthreads();
                if (kh == 0) {
                    f32x4 p0 = pred[mt][0][lane], p1 = pred[mt][1][lane];
#pragma unroll
                    for (int r = 0; r < 4; ++r) {
                        // sc1: consumed within this dispatch by col-block hk
                        astf(&zx[((size_t)t * BATCH + zr0 + r) * 4096 + ncolh],      s0[r] + p0[r] + bv0);
                        astf(&zx[((size_t)t * BATCH + zr0 + r) * 4096 + ncolh + 16], s1[r] + p1[r] + bv1);
                    }
                }
                drain_vm();
                __syncthreads();   // all writer waves drained + pred WAR
                if (tid == 0) ast(&bar3[hk * AR_STRIDE], (unsigned)(t + 1));
            }
            __syncthreads();
        }

        // ---- zx(next) helpers (mode 0 and mode 2 phase 2) ----
        {
            const __bf16* hi_src = Wn + ((size_t)(hk << 5)) * 2048;
            const __bf16* lo_src = Wn + ((size_t)(4096 + (hk << 5))) * 2048;
            for (int i = tid; i < 8192; i += 256) {
                int pl = i >> 12, rem = i & 4095;
                int r = rem >> 7, cc = rem & 127;
                const __bf16* s = (pl ? lo_src : hi_src) + (size_t)r * 2048 + cc * 8;
                bf16x8 v = *(const bf16x8*)s;
                int rnt = r >> 4, rq = r & 15, kc = cc >> 2, rg = cc & 3;
                *(bf16x8*)&wl[pl][((rnt * 32 + kc) << 9) + ((rg * 16 + rq) << 3)] = v;
            }
        }
        float bv0 = 0.f, bv1 = 0.f;
        if (kh == 0) { bv0 = bias_n[ncolh]; bv1 = bias_n[ncolh + 16]; }
        __syncthreads();
        const __bf16* hb0 = &wl[0][0]        + (lane << 3);
        const __bf16* lb0 = &wl[1][0]        + (lane << 3);
        const __bf16* hb1 = &wl[0][32 << 9]  + (lane << 3);
        const __bf16* lb1 = &wl[1][32 << 9]  + (lane << 3);

        for (int t = 0; t < SEQ; ++t) {
            const unsigned gen = gen0 + (unsigned)t + 1u;
            if (tid < BATCH) {     // wait for h(l)[t]
                while (ald(&bar2[tid * AR_STRIDE]) < gen) __builtin_amdgcn_s_sleep(1);
            }
            __syncthreads();
            const __bf16* ah = xhi + ((size_t)t * BATCH + (mt << 4) + q) * RNN;
            const __bf16* al = xlo + ((size_t)t * BATCH + (mt << 4) + q) * RNN;
            f32x4 a00={0,0,0,0}, a01={0,0,0,0}, a02={0,0,0,0};
            f32x4 a10={0,0,0,0}, a11={0,0,0,0}, a12={0,0,0,0};
            const int k0 = kh << 4;
#pragma unroll 4
            for (int kc = k0; kc < k0 + 16; ++kc) {
                bf16x8 ahf = *(const bf16x8*)(ah + (kc << 5) + (g << 3));
                bf16x8 alf = *(const bf16x8*)(al + (kc << 5) + (g << 3));
                bf16x8 b0h = *(const bf16x8*)(hb0 + (kc << 9));
                bf16x8 b0l = *(const bf16x8*)(lb0 + (kc << 9));
                bf16x8 b1h = *(const bf16x8*)(hb1 + (kc << 9));
                bf16x8 b1l = *(const bf16x8*)(lb1 + (kc << 9));
                a00 = __builtin_amdgcn_mfma_f32_16x16x32_bf16(ahf, b0h, a00, 0, 0, 0);
                a01 = __builtin_amdgcn_mfma_f32_16x16x32_bf16(alf, b0h, a01, 0, 0, 0);
                a02 = __builtin_amdgcn_mfma_f32_16x16x32_bf16(ahf, b0l, a02, 0, 0, 0);
                a10 = __builtin_amdgcn_mfma_f32_16x16x32_bf16(ahf, b1h, a10, 0, 0, 0);
                a11 = __builtin_amdgcn_mfma_f32_16x16x32_bf16(alf, b1h, a11, 0, 0, 0);
                a12 = __builtin_amdgcn_mfma_f32_16x16x32_bf16(ahf, b1l, a12, 0, 0, 0);
            }
            f32x4 s0, s1;
#pragma unroll
            for (int j = 0; j < 4; ++j) {
                s0[j] = a00[j] + a01[j] + a02[j];
                s1[j] = a10[j] + a11[j] + a12[j];
            }
            if (kh == 1) { pred[mt][0][lane] = s0; pred[mt][1][lane] = s1; }
            __syncthreads();
            if (kh == 0) {
                f32x4 p0 = pred[mt][0][lane], p1 = pred[mt][1][lane];
#pragma unroll
                for (int r = 0; r < 4; ++r) {
                    zx[((size_t)t * BATCH + zr0 + r) * 4096 + ncolh]      = s0[r] + p0[r] + bv0;
                    zx[((size_t)t * BATCH + zr0 + r) * 4096 + ncolh + 16] = s1[r] + p1[r] + bv1;
                }
            }
            __syncthreads();   // pred WAR across t
        }
        return;
    }

    // ======================= recurrence blocks (0..127) =====================
    const int ncol = (bk << 5) + q;       // nt=0 col; nt=1 at +16

    // ---- stage Wh hi+lo into LDS (lane-read order) ----
    {
        const __bf16* hi_src = Wl + ((size_t)(bk << 5)) * 2048 + RNN;
        const __bf16* lo_src = Wl + ((size_t)(4096 + (bk << 5))) * 2048 + RNN;
        for (int i = tid; i < 8192; i += 256) {
            int pl = i >> 12, rem = i & 4095;
            int r = rem >> 7, cc = rem & 127;
            const __bf16* s = (pl ? lo_src : hi_src) + (size_t)r * 2048 + cc * 8;
            bf16x8 v = *(const bf16x8*)s;
            int rnt = r >> 4, rq = r & 15, kc = cc >> 2, rg = cc & 3;
            *(bf16x8*)&wl[pl][((rnt * 32 + kc) << 9) + ((rg * 16 + rq) << 3)] = v;
        }
    }

    // ---- gate-block constants (blocks 0..31) ----
    const bool is_gate = (bk < BATCH);
    f32x4 gi, bi, gj, bj, gf, bfv, go, bo, g4, b4;
    if (is_gate) {
        gi = *(const f32x4*)(g5 + 0*RNN + tid*4); bi = *(const f32x4*)(b5 + 0*RNN + tid*4);
        gj = *(const f32x4*)(g5 + 1*RNN + tid*4); bj = *(const f32x4*)(b5 + 1*RNN + tid*4);
        gf = *(const f32x4*)(g5 + 2*RNN + tid*4); bfv= *(const f32x4*)(b5 + 2*RNN + tid*4);
        go = *(const f32x4*)(g5 + 3*RNN + tid*4); bo = *(const f32x4*)(b5 + 3*RNN + tid*4);
        g4 = *(const f32x4*)(g5 + 4*RNN + tid*4); b4 = *(const f32x4*)(b5 + 4*RNN + tid*4);
    }
    const float inv = 1.f / (float)RNN;
    f32x4 creg = {0.f, 0.f, 0.f, 0.f};    // cell state lives in registers
    __syncthreads();   // LDS staged

    const __bf16* bh0 = &wl[0][0]        + (lane << 3);   // nt=0 hi (+kc<<9)
    const __bf16* bl0 = &wl[1][0]        + (lane << 3);   // nt=0 lo
    const __bf16* bh1 = &wl[0][32 << 9]  + (lane << 3);   // nt=1 hi
    const __bf16* bl1 = &wl[1][32 << 9]  + (lane << 3);   // nt=1 lo

    // zx prefetch (t = 0), kh0 waves only (they finalize z)
    float zv0[4], zv1[4];
    if (kh == 0) {
        if (mode == 2) {   // l=0: wait for in-launch zx(0)[0]
            while (ald(&bar3[bk * AR_STRIDE]) < 1u) __builtin_amdgcn_s_sleep(1);
        }
        const float* zxp = zx + (size_t)zr0 * 4096 + ncol;
#pragma unroll
        for (int r = 0; r < 4; ++r) {
            zv0[r] = zxp[(size_t)r * 4096];
            zv1[r] = zxp[(size_t)r * 4096 + 16];
        }
    }

    for (int t = 0; t < SEQ; ++t) {
        const unsigned gen = gen0 + (unsigned)t + 1u;
        // ---- phase A: z_t = zx[t] + h_{t-1} @ Wh (K-split across waves) ----
        f32x4 a00={0,0,0,0}, a01={0,0,0,0}, a02={0,0,0,0};
        f32x4 a10={0,0,0,0}, a11={0,0,0,0}, a12={0,0,0,0};
        if (t > 0) {
            const __bf16* ah = xhi + ((size_t)(t - 1) * BATCH + (mt << 4) + q) * RNN;
            const __bf16* al = xlo + ((size_t)(t - 1) * BATCH + (mt << 4) + q) * RNN;
            const int k0 = kh << 4;
#pragma unroll 4
            for (int kc = k0; kc < k0 + 16; ++kc) {
                bf16x8 ahf = *(const bf16x8*)(ah + (kc << 5) + (g << 3));   // normal 16B
                bf16x8 alf = *(const bf16x8*)(al + (kc << 5) + (g << 3));
                bf16x8 b0h = *(const bf16x8*)(bh0 + (kc << 9));
                bf16x8 b0l = *(const bf16x8*)(bl0 + (kc << 9));
                bf16x8 b1h = *(const bf16x8*)(bh1 + (kc << 9));
                bf16x8 b1l = *(const bf16x8*)(bl1 + (kc << 9));
                a00 = __builtin_amdgcn_mfma_f32_16x16x32_bf16(ahf, b0h, a00, 0, 0, 0);
                a01 = __builtin_amdgcn_mfma_f32_16x16x32_bf16(alf, b0h, a01, 0, 0, 0);
                a02 = __builtin_amdgcn_mfma_f32_16x16x32_bf16(ahf, b0l, a02, 0, 0, 0);
                a10 = __builtin_amdgcn_mfma_f32_16x16x32_bf16(ahf, b1h, a10, 0, 0, 0);
                a11 = __builtin_amdgcn_mfma_f32_16x16x32_bf16(alf, b1h, a11, 0, 0, 0);
                a12 = __builtin_amdgcn_mfma_f32_16x16x32_bf16(ahf, b1l, a12, 0, 0, 0);
            }
        }
        {
            f32x4 s0, s1;
#pragma unroll
            for (int j = 0; j < 4; ++j) {
                s0[j] = a00[j] + a01[j] + a02[j];
                s1[j] = a10[j] + a11[j] + a12[j];
            }
            if (kh == 1) { pred[mt][0][lane] = s0; pred[mt][1][lane] = s1; }
            __syncthreads();
            if (kh == 0) {
                f32x4 p0 = pred[mt][0][lane], p1 = pred[mt][1][lane];
#pragma unroll
                for (int r = 0; r < 4; ++r) {
                    astf(&z[(size_t)(zr0 + r) * 4096 + ncol],      s0[r] + p0[r] + zv0[r]);
                    astf(&z[(size_t)(zr0 + r) * 4096 + ncol + 16], s1[r] + p1[r] + zv1[r]);
                }
            }
        }
        bar_all(bar, bk, tid, gen, is_gate);   // z visible (only gates wait)

        // ---- prefetch zx for t+1 (hides under phase B) ----
        if (kh == 0 && t + 1 < SEQ) {
            if (mode == 2) {   // l=0: wait for in-launch zx(0)[t+1]
                while (ald(&bar3[bk * AR_STRIDE]) < (unsigned)(t + 2))
                    __builtin_amdgcn_s_sleep(1);
            }
            const float* zxp = zx + ((size_t)(t + 1) * BATCH + zr0) * 4096 + ncol;
#pragma unroll
            for (int r = 0; r < 4; ++r) {
                zv0[r] = zxp[(size_t)r * 4096];
                zv1[r] = zxp[(size_t)r * 4096 + 16];
            }
        }

        // ---- phase B: gates (blocks 0..31), c in registers ----
        if (is_gate) {
            const int b = bk;
            const float* zrow = z + (size_t)b * 4096 + tid * 4;
            auto ld4 = [&](const float* p) -> f32x4 {
                U128F x;
                x.u[0] = ald64((const unsigned long long*)p);
                x.u[1] = ald64((const unsigned long long*)p + 1);
                return x.f;
            };
            f32x4 zi = ld4(zrow), zjv = ld4(zrow + 1024),
                  zfv = ld4(zrow + 2048), zov = ld4(zrow + 3072);
            float s[8];
            s[0] = zi[0]+zi[1]+zi[2]+zi[3];
            s[1] = zi[0]*zi[0]+zi[1]*zi[1]+zi[2]*zi[2]+zi[3]*zi[3];
            s[2] = zjv[0]+zjv[1]+zjv[2]+zjv[3];
            s[3] = zjv[0]*zjv[0]+zjv[1]*zjv[1]+zjv[2]*zjv[2]+zjv[3]*zjv[3];
            s[4] = zfv[0]+zfv[1]+zfv[2]+zfv[3];
            s[5] = zfv[0]*zfv[0]+zfv[1]*zfv[1]+zfv[2]*zfv[2]+zfv[3]*zfv[3];
            s[6] = zov[0]+zov[1]+zov[2]+zov[3];
            s[7] = zov[0]*zov[0]+zov[1]*zov[1]+zov[2]*zov[2]+zov[3]*zov[3];
#pragma unroll
            for (int o = 32; o; o >>= 1)
#pragma unroll
                for (int i = 0; i < 8; ++i) s[i] += __shfl_xor(s[i], o);
            if (lane == 0) {
#pragma unroll
                for (int i = 0; i < 8; ++i) red[w][i] = s[i];
            }
            __syncthreads();
            float tot[8];
#pragma unroll
            for (int i = 0; i < 8; ++i) tot[i] = red[0][i]+red[1][i]+red[2][i]+red[3][i];

            float mi = tot[0]*inv, ri = rsqrtf(tot[1]*inv - mi*mi + 1e-5f);
            float mj = tot[2]*inv, rj = rsqrtf(tot[3]*inv - mj*mj + 1e-5f);
            float mf = tot[4]*inv, rf = rsqrtf(tot[5]*inv - mf*mf + 1e-5f);
            float mo = tot[6]*inv, ro = rsqrtf(tot[7]*inv - mo*mo + 1e-5f);

            f32x4 onrm;
            float cs = 0.f, cq = 0.f;
#pragma unroll
            for (int j = 0; j < 4; ++j) {
                float iv = (zi[j]-mi)*ri*gi[j] + bi[j];
                float jv = (zjv[j]-mj)*rj*gj[j] + bj[j];
                float fv = (zfv[j]-mf)*rf*gf[j] + bfv[j];
                float ov = (zov[j]-mo)*ro*go[j] + bo[j];
                float cc = creg[j] * sigm(fv + 1.0f) + sigm(iv) * tanhf(jv);
                creg[j] = cc; onrm[j] = ov;
                cs += cc; cq += cc*cc;
            }

            __syncthreads();   // protect red[] reuse
            float s2a = cs, s2b = cq;
#pragma unroll
            for (int o = 32; o; o >>= 1) { s2a += __shfl_xor(s2a, o); s2b += __shfl_xor(s2b, o); }
            if (lane == 0) { red[w][0] = s2a; red[w][1] = s2b; }
            __syncthreads();
            float mc = (red[0][0]+red[1][0]+red[2][0]+red[3][0]) * inv;
            float vc = (red[0][1]+red[1][1]+red[2][1]+red[3][1]) * inv - mc*mc;
            float rc = rsqrtf(vc + 1e-5f);

            bf16x4 hh, hl;
#pragma unroll
            for (int j = 0; j < 4; ++j) {
                float cn = (creg[j]-mc)*rc*g4[j] + b4[j];
                float h = tanhf(cn) * sigm(onrm[j]);
                __bf16 a = (__bf16)h;
                hh[j] = a; hl[j] = (__bf16)(h - (float)a);
            }
            U64B ph, pl;
            ph.v = hh; pl.v = hl;
            // single h store: time-indexed x buffers (sc1 -> coherence point)
            ast64((unsigned long long*)&xhi[((size_t)t * BATCH + b) * RNN + tid * 4], ph.u);
            ast64((unsigned long long*)&xlo[((size_t)t * BATCH + b) * RNN + tid * 4], pl.u);
        }
        bar_gate(bar2, bk, is_gate, tid, gen);   // h visible
    }
}

// ---------------------------------------------------------------------------
extern "C" void kernel_launch(void* const* d_in, const int* in_sizes, int n_in,
                              void* d_out, int out_size, void* d_ws, size_t ws_size,
                              hipStream_t stream) {
    const int*   input = (const int*)  d_in[0];
    const float* emb   = (const float*)d_in[1];
    const float* W     = (const float*)d_in[2];
    const float* bias  = (const float*)d_in[3];
    const float* ln_g  = (const float*)d_in[4];
    const float* ln_b  = (const float*)d_in[5];
    const float* smw   = (const float*)d_in[6];
    const float* smb   = (const float*)d_in[7];
    float* out = (float*)d_out;

    char* p = (char*)d_ws;
    auto alloc = [&](size_t bytes) { char* r = p; p += (bytes + 255) & ~(size_t)255; return r; };
    __bf16* Wt   = (__bf16*)alloc((size_t)NLAY * 2 * 4096 * 2048 * 2); // 134.2 MB
    __bf16* smwb = (__bf16*)alloc((size_t)VOCAB * RNN * 2);            // 65.5 MB
    __bf16* xhi  = (__bf16*)alloc((size_t)SEQ * BATCH * RNN * 2);      // 8.4 MB
    __bf16* xlo  = (__bf16*)alloc((size_t)SEQ * BATCH * RNN * 2);      // 8.4 MB
    float*  zx   = (float*) alloc((size_t)SEQ * BATCH * 4096 * 4);     // 67.1 MB
    float*  z    = (float*) alloc((size_t)BATCH * 4096 * 4);           // 512 KB
    unsigned* bar= (unsigned*)alloc(3 * GBLK * AR_STRIDE * 4);         // z, h, zx0

    hipMemsetAsync(bar, 0, 3 * GBLK * AR_STRIDE * 4, stream);

    k_cvt_w<<<dim3(64, 32, NLAY), 256, 0, stream>>>(W, Wt);
    k_cvt<<<(VOCAB * RNN) / (8 * 256), 256, 0, stream>>>(smw, smwb);
    k_embed<<<SEQ * BATCH, 256, 0, stream>>>(input, emb, xhi, xlo);

    for (int l = 0; l < NLAY; ++l) {
        const __bf16* Wl  = Wt + (size_t)l * 2 * 4096 * 2048;
        const float*  gl  = ln_g + (size_t)l * 5 * RNN;
        const float*  bbl = ln_b + (size_t)l * 5 * RNN;
        const int lnext = (l + 1 < NLAY) ? (l + 1) : l;   // dummy for l=3
        const __bf16* Wn  = Wt + (size_t)lnext * 2 * 4096 * 2048;
        const float*  bn  = bias + (size_t)lnext * 4096;
        {
            const __bf16* Wl_ = Wl;
            float* zx_ = zx;
            float* z_ = z;
            __bf16 *xhi_ = xhi, *xlo_ = xlo;
            const float *gl_ = gl, *bbl_ = bbl;
            unsigned* bar_ = bar;
            unsigned gen0 = (unsigned)(l * SEQ);
            const __bf16* Wn_ = Wn;
            const float* bn_ = bn;
            const float* bl_ = bias + (size_t)l * 4096;
            // mode: 2 = l0 (zx0 pre-phase + zx1), 0 = l1/l2 (zx next), 1 = l3 (proj)
            int mode = (l == 0) ? 2 : ((l + 1 < NLAY) ? 0 : 1);
            const __bf16* pw_ = smwb;
            const float* psb_ = smb;
            float* pout_ = out;
            void* args[] = {(void*)&Wl_, (void*)&zx_, (void*)&z_,
                            (void*)&xhi_, (void*)&xlo_, (void*)&gl_, (void*)&bbl_,
                            (void*)&bar_, (void*)&gen0, (void*)&Wn_, (void*)&bn_,
                            (void*)&bl_,
                            (void*)&mode, (void*)&pw_, (void*)&psb_, (void*)&pout_};
            hipLaunchCooperativeKernel((const void*)k_rnn,
                                       dim3(2 * GBLK), dim3(256), args, 0, stream);
        }
    }
    // projection is produced inside the l=3 launch (proj helpers)
}